// Round 11
// baseline (316.622 us; speedup 1.0000x reference)
//
#include <hip/hip_runtime.h>
#include <math.h>

#define B_ 4
#define C_ 128
#define HW_ 16384
#define P_ 65536
#define S_ 8388608   // B*C*H*W elements
#define CPG 8        // channels per group (128/16)

typedef unsigned short u16;
typedef __attribute__((ext_vector_type(8))) short short8;
typedef __attribute__((ext_vector_type(4))) float f32x4;

__device__ __forceinline__ float sigmoidf_(float x){ return 1.f/(1.f+__expf(-x)); }
__device__ __forceinline__ float siluf_(float x){ return x*sigmoidf_(x); }
__device__ __forceinline__ u16 f2bf(float f){
  unsigned x = __float_as_uint(f);
  return (u16)((x + 0x7fffu + ((x >> 16) & 1u)) >> 16);
}
__device__ __forceinline__ float b2f(u16 u){ return __uint_as_float(((unsigned)u) << 16); }

// Build wfrag (dyn_w in MFMA A-fragment order), bperm, wgbf, wobf, wibf, stats=0.
__global__ __launch_bounds__(256) void prep_kernel(const float* __restrict__ dyn_w,
    const float* __restrict__ dyn_b, const float* __restrict__ w_gate,
    const float* __restrict__ w_out, const float* __restrict__ w_in,
    u16* __restrict__ wfrag, float* __restrict__ bperm, u16* __restrict__ wgbf,
    u16* __restrict__ wobf, u16* __restrict__ wibf, float* __restrict__ stats)
{
  int idx = blockIdx.x*256 + threadIdx.x;
  if (idx < 262144) {
    int e = idx & 7, lane = (idx >> 3) & 63, kk = (idx >> 9) & 3;
    int ct = (idx >> 11) & 31, d = idx >> 16;
    int m = lane & 15, kg = lane >> 4;
    int col = ct*16 + m;
    int c = col >> 2, f = col & 3;
    int k = kk*32 + kg*8 + e;
    wfrag[idx] = f2bf(dyn_w[(size_t)((d*512) + f*128 + c)*128 + k]);
  } else if (idx < 264192) {
    int i2 = idx - 262144;
    int op = i2 & 511, d = i2 >> 9;
    bperm[i2] = dyn_b[d*512 + (op & 3)*128 + (op >> 2)];
  } else if (idx < 280576) {
    wgbf[idx - 264192] = f2bf(w_gate[idx - 264192]);
  } else if (idx < 296960) {
    wobf[idx - 280576] = f2bf(w_out[idx - 280576]);
  } else if (idx < 313344) {
    wibf[idx - 296960] = f2bf(w_in[idx - 296960]);
  } else if (idx < 313600) {
    stats[idx - 313344] = 0.f;
  }
}

// in_proj MFMA GEMM reading channels-first fp32 x directly.
__global__ __launch_bounds__(256) void mfma_inproj(const float* __restrict__ x,
    const u16* __restrict__ Wm, u16* __restrict__ Out)
{
  __shared__ __align__(16) u16 st[64*136];
  int t = threadIdx.x;
  int wv = t >> 6, lane = t & 63;
  int m = lane & 15, kg = lane >> 4;
  int pt = blockIdx.x << 6;
  int b = blockIdx.x >> 8;
  int hw0 = (blockIdx.x & 255) << 6;
  const float* xb = x + ((size_t)b << 21);

  short8 Af[4][4];
  #pragma unroll
  for (int rt = 0; rt < 4; ++rt) {
    int pos = hw0 + rt*16 + m;
    #pragma unroll
    for (int kk = 0; kk < 4; ++kk) {
      short8 f;
      #pragma unroll
      for (int e = 0; e < 8; ++e)
        f[e] = (short)f2bf(xb[(size_t)(kk*32 + kg*8 + e)*HW_ + pos]);
      Af[rt][kk] = f;
    }
  }
  #pragma unroll
  for (int ct2 = 0; ct2 < 2; ++ct2) {
    int ot = wv*32 + ct2*16;
    const u16* wr = Wm + ((size_t)(ot + m) << 7) + kg*8;
    short8 Bf[4];
    #pragma unroll
    for (int kk = 0; kk < 4; ++kk)
      Bf[kk] = *(const short8*)(wr + kk*32);
    f32x4 acc[4];
    #pragma unroll
    for (int rt = 0; rt < 4; ++rt) acc[rt] = (f32x4){0.f,0.f,0.f,0.f};
    #pragma unroll
    for (int rt = 0; rt < 4; ++rt)
      #pragma unroll
      for (int kk = 0; kk < 4; ++kk)
        acc[rt] = __builtin_amdgcn_mfma_f32_16x16x32_bf16(Af[rt][kk], Bf[kk], acc[rt], 0, 0, 0);
    #pragma unroll
    for (int rt = 0; rt < 4; ++rt) {
      #pragma unroll
      for (int r = 0; r < 4; ++r)
        st[(rt*16 + kg*4 + r)*136 + ot + m] = f2bf(acc[rt][r]);
    }
  }
  __syncthreads();
  #pragma unroll
  for (int i = 0; i < 4; ++i) {
    int slot = i*256 + t;
    int row = slot >> 4, j = slot & 15;
    short8 v = *(const short8*)(st + row*136 + (j << 3));
    *(short8*)(Out + ((size_t)(pt + row) << 7) + (j << 3)) = v;
  }
}

// MFMA NT GEMM, O=128, LDS-staged coalesced output.
template<int BIAS, int SIG>
__global__ __launch_bounds__(256) void mfma_nt128(const u16* __restrict__ X,
    const u16* __restrict__ Wm, const float* __restrict__ bias, u16* __restrict__ Out)
{
  __shared__ __align__(16) u16 st[64*136];
  int t = threadIdx.x;
  int wv = t >> 6, lane = t & 63;
  int m = lane & 15, kg = lane >> 4;
  int pt = blockIdx.x << 6;

  short8 Af[4][4];
  #pragma unroll
  for (int rt = 0; rt < 4; ++rt) {
    const u16* ar = X + ((size_t)(pt + rt*16 + m) << 7) + kg*8;
    #pragma unroll
    for (int kk = 0; kk < 4; ++kk)
      Af[rt][kk] = *(const short8*)(ar + kk*32);
  }
  #pragma unroll
  for (int ct2 = 0; ct2 < 2; ++ct2) {
    int ot = wv*32 + ct2*16;
    const u16* wr = Wm + ((size_t)(ot + m) << 7) + kg*8;
    short8 Bf[4];
    #pragma unroll
    for (int kk = 0; kk < 4; ++kk)
      Bf[kk] = *(const short8*)(wr + kk*32);
    f32x4 acc[4];
    #pragma unroll
    for (int rt = 0; rt < 4; ++rt) acc[rt] = (f32x4){0.f,0.f,0.f,0.f};
    #pragma unroll
    for (int rt = 0; rt < 4; ++rt)
      #pragma unroll
      for (int kk = 0; kk < 4; ++kk)
        acc[rt] = __builtin_amdgcn_mfma_f32_16x16x32_bf16(Af[rt][kk], Bf[kk], acc[rt], 0, 0, 0);
    float bv = BIAS ? bias[ot + m] : 0.f;
    #pragma unroll
    for (int rt = 0; rt < 4; ++rt) {
      #pragma unroll
      for (int r = 0; r < 4; ++r) {
        float v = acc[rt][r] + bv;
        if (SIG) v = sigmoidf_(v);
        st[(rt*16 + kg*4 + r)*136 + ot + m] = f2bf(v);
      }
    }
  }
  __syncthreads();
  #pragma unroll
  for (int i = 0; i < 4; ++i) {
    int slot = i*256 + t;
    int row = slot >> 4, j = slot & 15;
    short8 v = *(const short8*)(st + row*136 + (j << 3));
    *(short8*)(Out + ((size_t)(pt + row) << 7) + (j << 3)) = v;
  }
}

// Produce 16-pos coeff chunk (4 tiles, this wave's dir) into cs double buffer.
#define PRODUCE2(chunkv, bufv)  do { \
  int posg_ = (chunkv)*16 + m; int swp_ = (posg_ & 7) << 4; \
  short8 Bfr[4]; \
  _Pragma("unroll") for (int kk = 0; kk < 4; ++kk) \
    Bfr[kk] = *(const short8*)((char*)xs + posg_*256 + (((kk<<6)+(kg<<4)) ^ swp_)); \
  _Pragma("unroll") for (int ti = 0; ti < 4; ++ti) { \
    f32x4 acc = (f32x4){0.f,0.f,0.f,0.f}; \
    _Pragma("unroll") for (int kk = 0; kk < 4; ++kk) \
      acc = __builtin_amdgcn_mfma_f32_16x16x32_bf16(Af[ti][kk], Bfr[kk], acc, 0, 0, 0); \
    int colL_ = (tbase + ti)*16 + (kg<<2); \
    unsigned lo_ = (unsigned)f2bf(acc[0]) | ((unsigned)f2bf(acc[1])<<16); \
    unsigned hi_ = (unsigned)f2bf(acc[2]) | ((unsigned)f2bf(acc[3])<<16); \
    int byte_ = (((bufv)*2 + dw)<<14) + (m<<10) + ((colL_<<1) ^ ((m&7)<<4)); \
    *(uint2*)((char*)cs + byte_) = make_uint2(lo_, hi_); \
  } } while(0)

#define SCAN_STEP(s) { \
  float ar = b2f((u16)(cw[s].x & 0xffffu)) + bv.x; \
  float br = b2f((u16)(cw[s].x >> 16)) + bv.y; \
  float cr = b2f((u16)(cw[s].y & 0xffffu)) + bv.z; \
  float dr = b2f((u16)(cw[s].y >> 16)) + bv.w; \
  float aa = sigmoidf_(ar); \
  h = aa*h + br*xf[s]; \
  yv[s] = cr*h + dr*xf[s]; }

// Fused coeff-GEMM + bidirectional scan. Block = 1024 thr (16 waves); EVERY wave
// produces exactly 4 W-tiles (64 VGPR, register-resident). Waves 0-3 also scan
// (wv0,1 = fwd ch 0..127; wv2,3 = rev). Scanner tiles 0-7/dir; producer waves
// 4-15 cover tiles 8-31/dir (6 waves per dir). All barriers uniform.
// AXISW=1: lines along W (lr/rl), PART=0 store. AXISW=0: along H, PART=1 RMW.
template<int AXISW, int PART>
__global__ __launch_bounds__(1024) void scan_fused(const u16* __restrict__ Abf,
    const u16* __restrict__ Wf, const float* __restrict__ bias,
    u16* __restrict__ fusedP)
{
  __shared__ __align__(16) u16 xs[128*128];      // 32 KB, swizzled byte ^ ((pos&7)<<4)
  __shared__ __align__(16) u16 cs[2][2][16*512]; // 64 KB: [buf][dir][16 pos][512 cols]
  __shared__ __align__(16) u16 ysL[128*128];     // 32 KB bf16 partial y [pos][ch]
  int line = blockIdx.x;
  int b = line >> 7, l = line & 127;
  int t = threadIdx.x;
  int wv = t >> 6, lane = t & 63;
  int m = lane & 15, kg = lane >> 4;
  int dw, tbase;
  if (wv < 4) { dw = (wv >> 1) & 1; tbase = (wv & 1) * 4; }
  else        { int pw = wv - 4; dw = pw & 1; tbase = 8 + (pw >> 1) * 4; }

  // stage xp tile for the line (128 pos x 128 ch): 2048 short8 chunks
  #pragma unroll
  for (int i = 0; i < 2; ++i) {
    int idx = i*1024 + t;
    int pos = idx >> 4, j = idx & 15;
    size_t row = AXISW ? ((size_t)(b<<14) + (l<<7) + pos)
                       : ((size_t)(b<<14) + (pos<<7) + l);
    short8 v = *(const short8*)(Abf + (row<<7) + (j<<3));
    int byte = pos*256 + ((j*16) ^ ((pos&7)<<4));
    *(short8*)((char*)xs + byte) = v;
  }

  // W fragments: 4 tiles per wave, register-resident
  short8 Af[4][4];
  #pragma unroll
  for (int ti = 0; ti < 4; ++ti)
    #pragma unroll
    for (int kk = 0; kk < 4; ++kk)
      Af[ti][kk] = *(const short8*)(Wf + (size_t)(((dw*32 + tbase + ti)*4 + kk)*64 + lane)*8);

  __syncthreads();                       // xs ready
  PRODUCE2(dw ? 7 : 0, 0);
  __syncthreads();                       // cs[0] ready

  int sd = dw;
  int sc = ((wv & 1) << 6) + lane;       // scan channel (waves 0-3 only)
  float4 bv = make_float4(0.f, 0.f, 0.f, 0.f);
  if (wv < 4) bv = *(const float4*)(bias + (sd << 9) + (sc << 2));
  float h = 0.f;

  #pragma unroll 1
  for (int k = 0; k < 8; ++k) {
    if (k < 7) PRODUCE2(dw ? (6-k) : (k+1), (k+1)&1);
    if (wv < 4) {
      int chunk = sd ? (7-k) : k;
      int csb = (((k&1)*2 + sd) << 14);
      #pragma unroll
      for (int hh = 0; hh < 2; ++hh) {
        uint2 cw[8]; float xf[8];
        #pragma unroll
        for (int s = 0; s < 8; ++s) {
          int posL = sd ? (15 - (hh*8 + s)) : (hh*8 + s);
          cw[s] = *(const uint2*)((char*)cs + csb + (posL<<10) + ((sc<<3) ^ ((posL&7)<<4)));
          int pos = (chunk<<4) + posL;
          xf[s] = b2f(*(const u16*)((char*)xs + pos*256 + ((sc<<1) ^ ((posL&7)<<4))));
        }
        float yv[8];
        __builtin_amdgcn_s_setprio(1);
        #pragma unroll
        for (int s = 0; s < 8; ++s) SCAN_STEP(s)
        __builtin_amdgcn_s_setprio(0);
        #pragma unroll
        for (int s = 0; s < 8; ++s) {
          int posL = sd ? (15 - (hh*8 + s)) : (hh*8 + s);
          u16* yp = ysL + (((chunk<<4) + posL) << 7) + sc;
          if (k <= 3) *yp = f2bf(0.25f*yv[s]);
          else        *yp = f2bf(b2f(*yp) + 0.25f*yv[s]);
        }
      }
    }
    __syncthreads();
  }

  // cooperative coalesced writeout: 2048 short8 slots
  #pragma unroll
  for (int r = 0; r < 2; ++r) {
    int slot = r*1024 + t;
    int pos = slot >> 4, j = slot & 15;
    short8 v = *(const short8*)(ysL + (pos << 7) + (j << 3));
    size_t rowg = AXISW ? ((size_t)(b<<14) + (l<<7) + pos)
                        : ((size_t)(b<<14) + (pos<<7) + l);
    u16* op = fusedP + (rowg << 7) + (j << 3);
    if (PART) {
      short8 o = *(const short8*)op;
      short8 rr;
      #pragma unroll
      for (int i = 0; i < 8; ++i) rr[i] = (short)f2bf(b2f((u16)v[i]) + b2f((u16)o[i]));
      *(short8*)op = rr;
    } else {
      *(short8*)op = v;
    }
  }
}

// GroupNorm stats over bf16 channels-last, coalesced short8 loads.
__global__ __launch_bounds__(256) void gn_stats_bf(const u16* __restrict__ X,
    float* __restrict__ stats)
{
  int b = blockIdx.x, chunk = blockIdx.y;
  const u16* base = X + ((size_t)b << 21) + ((size_t)chunk << 15);
  int t = threadIdx.x;
  float s = 0.f, q = 0.f;
  #pragma unroll 4
  for (int it = 0; it < 16; ++it) {
    short8 v = *(const short8*)(base + it*2048 + t*8);
    #pragma unroll
    for (int e = 0; e < 8; ++e) { float f = b2f((u16)v[e]); s += f; q += f*f; }
  }
  s += __shfl_xor(s, 16); q += __shfl_xor(q, 16);
  s += __shfl_xor(s, 32); q += __shfl_xor(q, 32);
  __shared__ float sg[32];
  if (t < 32) sg[t] = 0.f;
  __syncthreads();
  int lane = t & 63;
  if (lane < 16) { atomicAdd(&sg[lane], s); atomicAdd(&sg[16 + lane], q); }
  __syncthreads();
  if (t < 16) atomicAdd(&stats[b*16 + t], sg[t]);
  else if (t < 32) atomicAdd(&stats[64 + b*16 + (t - 16)], sg[t]);
}

// Apply GN1 + SiLU: read bf16, write bf16.
__global__ __launch_bounds__(256) void gn_apply(const u16* __restrict__ X,
    const float* __restrict__ stats, const float* __restrict__ gamma,
    const float* __restrict__ beta, u16* __restrict__ Xb)
{
  int i4 = blockIdx.x*256 + threadIdx.x;
  size_t base = (size_t)i4 << 2;
  int c4 = (int)(base & 127);
  size_t p = base >> 7;
  int b = (int)(p >> 14);
  int g = c4 >> 3;
  const float cnt = (float)(CPG*HW_);
  float mu = stats[b*16+g]/cnt;
  float var = stats[64+b*16+g]/cnt - mu*mu;
  float rs = rsqrtf(var + 1e-5f);
  ushort4 v = *(const ushort4*)(X + base);
  ushort4 o;
  o.x = f2bf(siluf_((b2f(v.x)-mu)*rs*gamma[c4+0]+beta[c4+0]));
  o.y = f2bf(siluf_((b2f(v.y)-mu)*rs*gamma[c4+1]+beta[c4+1]));
  o.z = f2bf(siluf_((b2f(v.z)-mu)*rs*gamma[c4+2]+beta[c4+2]));
  o.w = f2bf(siluf_((b2f(v.w)-mu)*rs*gamma[c4+3]+beta[c4+3]));
  *(ushort4*)(Xb + base) = o;
}

// Depthwise 3x3 with fused gate multiply: z = dw3x3(fused * gate), bf16 in/out.
__global__ __launch_bounds__(256) void dwconv(const u16* __restrict__ Z,
    const u16* __restrict__ G, const float* __restrict__ K9, u16* __restrict__ Outp)
{
  __shared__ float kk[1152];
  int t = threadIdx.x;
  for (int i = t; i < 1152; i += 256) kk[i] = K9[i];
  __syncthreads();
  int i4 = blockIdx.x*256 + t;
  size_t base = (size_t)i4 << 2;
  int c0 = (int)(base & 127);
  size_t p = base >> 7;
  int w = (int)(p & 127), h = (int)((p >> 7) & 127), b = (int)(p >> 14);
  float4 acc = make_float4(0.f,0.f,0.f,0.f);
  #pragma unroll
  for (int di = 0; di < 3; ++di) {
    int hy = h + di - 1;
    if ((unsigned)hy > 127u) continue;
    #pragma unroll
    for (int dj = 0; dj < 3; ++dj) {
      int wx = w + dj - 1;
      if ((unsigned)wx > 127u) continue;
      size_t p2 = ((size_t)b << 14) + (hy << 7) + wx;
      ushort4 zv = *(const ushort4*)(Z + (p2 << 7) + c0);
      ushort4 gv = *(const ushort4*)(G + (p2 << 7) + c0);
      int o = di*3 + dj;
      acc.x += b2f(zv.x) * b2f(gv.x) * kk[c0*9 + o];
      acc.y += b2f(zv.y) * b2f(gv.y) * kk[(c0+1)*9 + o];
      acc.z += b2f(zv.z) * b2f(gv.z) * kk[(c0+2)*9 + o];
      acc.w += b2f(zv.w) * b2f(gv.w) * kk[(c0+3)*9 + o];
    }
  }
  ushort4 ov;
  ov.x = f2bf(acc.x); ov.y = f2bf(acc.y); ov.z = f2bf(acc.z); ov.w = f2bf(acc.w);
  *(ushort4*)(Outp + base) = ov;
}

// GN2 apply + SiLU + transpose to channels-first fp32 output. Input bf16.
__global__ __launch_bounds__(256) void gn_final(const u16* __restrict__ Z,
    const float* __restrict__ stats, const float* __restrict__ gamma,
    const float* __restrict__ beta, float* __restrict__ out)
{
  __shared__ float ls[32][129];
  int w0 = blockIdx.x << 5, hh = blockIdx.y, b = blockIdx.z;
  size_t p0 = ((size_t)b << 14) + (hh << 7) + w0;
  int t = threadIdx.x;
  const float cnt = (float)(CPG*HW_);
  #pragma unroll
  for (int i = 0; i < 4; ++i) {
    int l = t + i*256;
    int row = l >> 5, c4 = (l & 31) << 2;
    ushort4 v = *(const ushort4*)(Z + ((p0 + row) << 7) + c4);
    int g = c4 >> 3;
    float mu = stats[b*16+g]/cnt;
    float var = stats[64+b*16+g]/cnt - mu*mu;
    float rs = rsqrtf(var + 1e-5f);
    float vals[4] = {b2f(v.x), b2f(v.y), b2f(v.z), b2f(v.w)};
    #pragma unroll
    for (int j = 0; j < 4; ++j) {
      float nv = (vals[j]-mu)*rs*gamma[c4+j] + beta[c4+j];
      ls[row][c4+j] = siluf_(nv);
    }
  }
  __syncthreads();
  int ww = t & 31, c0 = t >> 5;
  #pragma unroll
  for (int cc = c0; cc < 128; cc += 8) {
    out[(((size_t)(b*128 + cc)) << 14) + (hh << 7) + (w0 + ww)] = ls[ww][cc];
  }
}

extern "C" void kernel_launch(void* const* d_in, const int* in_sizes, int n_in,
                              void* d_out, int out_size, void* d_ws, size_t ws_size,
                              hipStream_t stream)
{
  (void)in_sizes; (void)n_in; (void)out_size; (void)ws_size;
  const float* x      = (const float*)d_in[0];
  const float* w_in   = (const float*)d_in[1];
  const float* g1g    = (const float*)d_in[2];
  const float* g1b    = (const float*)d_in[3];
  const float* w_gate = (const float*)d_in[4];
  const float* b_gate = (const float*)d_in[5];
  const float* dyn_w  = (const float*)d_in[6];
  const float* dyn_b  = (const float*)d_in[7];
  const float* dwk    = (const float*)d_in[8];
  const float* w_out  = (const float*)d_in[9];
  const float* g2g    = (const float*)d_in[10];
  const float* g2b    = (const float*)d_in[11];
  float* out = (float*)d_out;

  char* p = (char*)d_ws;
  u16*   Zbuf   = (u16*)p;              p += (size_t)S_*2;   // scratch for Zdw
  u16*   xpr    = (u16*)p;              p += (size_t)S_*2;   // xp_raw bf16; later Zout
  u16*   Abf    = (u16*)p;              p += (size_t)S_*2;   // xp (post GN1+SiLU) bf16
  u16*   fusedP = (u16*)p;              p += (size_t)S_*2;   // fused partial/final bf16
  u16*   Gbf    = (u16*)p;              p += (size_t)S_*2;   // gate bf16
  u16*   wfrag  = (u16*)p;              p += (size_t)262144*2;
  u16*   wgbf   = (u16*)p;              p += (size_t)16384*2;
  u16*   wobf   = (u16*)p;              p += (size_t)16384*2;
  u16*   wibf   = (u16*)p;              p += (size_t)16384*2;
  float* bperm  = (float*)p;            p += (size_t)2048*4;
  float* stats  = (float*)p;            p += (size_t)256*4;
  u16*   Zdw    = Zbuf;
  u16*   Zout   = xpr;                  // alias (xp_raw dead after gn_apply)

  prep_kernel<<<1225, 256, 0, stream>>>(dyn_w, dyn_b, w_gate, w_out, w_in,
                                        wfrag, bperm, wgbf, wobf, wibf, stats);
  mfma_inproj<<<1024, 256, 0, stream>>>(x, wibf, xpr);
  gn_stats_bf<<<dim3(4, 64), 256, 0, stream>>>(xpr, stats);
  gn_apply<<<8192, 256, 0, stream>>>(xpr, stats, g1g, g1b, Abf);

  scan_fused<1,0><<<512, 1024, 0, stream>>>(Abf, wfrag, bperm, fusedP);
  scan_fused<0,1><<<512, 1024, 0, stream>>>(Abf, wfrag + 2*65536, bperm + 1024, fusedP);

  mfma_nt128<1,1><<<1024, 256, 0, stream>>>(Abf, wgbf, b_gate, Gbf);
  dwconv<<<8192, 256, 0, stream>>>(fusedP, Gbf, dwk, Zdw);
  mfma_nt128<0,0><<<1024, 256, 0, stream>>>(Zdw, wobf, nullptr, Zout);
  gn_stats_bf<<<dim3(4, 64), 256, 0, stream>>>(Zout, stats + 128);
  gn_final<<<dim3(4, 128, 4), 256, 0, stream>>>(Zout, stats + 128, g2g, g2b, out);
}

// Round 12
// 238.014 us; speedup vs baseline: 1.3303x; 1.3303x over previous
//
#include <hip/hip_runtime.h>
#include <math.h>

#define B_ 4
#define C_ 128
#define HW_ 16384
#define P_ 65536
#define S_ 8388608   // B*C*H*W elements
#define CPG 8        // channels per group (128/16)

typedef unsigned short u16;
typedef __attribute__((ext_vector_type(8))) short short8;
typedef __attribute__((ext_vector_type(4))) float f32x4;

__device__ __forceinline__ float sigmoidf_(float x){ return 1.f/(1.f+__expf(-x)); }
__device__ __forceinline__ float siluf_(float x){ return x*sigmoidf_(x); }
__device__ __forceinline__ u16 f2bf(float f){
  unsigned x = __float_as_uint(f);
  return (u16)((x + 0x7fffu + ((x >> 16) & 1u)) >> 16);
}
__device__ __forceinline__ float b2f(u16 u){ return __uint_as_float(((unsigned)u) << 16); }

// Build wfrag (dyn_w in MFMA A-fragment order), bperm, wgbf, wobf, wibf, stats=0.
__global__ __launch_bounds__(256) void prep_kernel(const float* __restrict__ dyn_w,
    const float* __restrict__ dyn_b, const float* __restrict__ w_gate,
    const float* __restrict__ w_out, const float* __restrict__ w_in,
    u16* __restrict__ wfrag, float* __restrict__ bperm, u16* __restrict__ wgbf,
    u16* __restrict__ wobf, u16* __restrict__ wibf, float* __restrict__ stats)
{
  int idx = blockIdx.x*256 + threadIdx.x;
  if (idx < 262144) {
    int e = idx & 7, lane = (idx >> 3) & 63, kk = (idx >> 9) & 3;
    int ct = (idx >> 11) & 31, d = idx >> 16;
    int m = lane & 15, kg = lane >> 4;
    int col = ct*16 + m;
    int c = col >> 2, f = col & 3;
    int k = kk*32 + kg*8 + e;
    wfrag[idx] = f2bf(dyn_w[(size_t)((d*512) + f*128 + c)*128 + k]);
  } else if (idx < 264192) {
    int i2 = idx - 262144;
    int op = i2 & 511, d = i2 >> 9;
    bperm[i2] = dyn_b[d*512 + (op & 3)*128 + (op >> 2)];
  } else if (idx < 280576) {
    wgbf[idx - 264192] = f2bf(w_gate[idx - 264192]);
  } else if (idx < 296960) {
    wobf[idx - 280576] = f2bf(w_out[idx - 280576]);
  } else if (idx < 313344) {
    wibf[idx - 296960] = f2bf(w_in[idx - 296960]);
  } else if (idx < 313600) {
    stats[idx - 313344] = 0.f;
  }
}

// in_proj MFMA GEMM reading channels-first fp32 x directly.
__global__ __launch_bounds__(256) void mfma_inproj(const float* __restrict__ x,
    const u16* __restrict__ Wm, u16* __restrict__ Out)
{
  __shared__ __align__(16) u16 st[64*136];
  int t = threadIdx.x;
  int wv = t >> 6, lane = t & 63;
  int m = lane & 15, kg = lane >> 4;
  int pt = blockIdx.x << 6;
  int b = blockIdx.x >> 8;
  int hw0 = (blockIdx.x & 255) << 6;
  const float* xb = x + ((size_t)b << 21);

  short8 Af[4][4];
  #pragma unroll
  for (int rt = 0; rt < 4; ++rt) {
    int pos = hw0 + rt*16 + m;
    #pragma unroll
    for (int kk = 0; kk < 4; ++kk) {
      short8 f;
      #pragma unroll
      for (int e = 0; e < 8; ++e)
        f[e] = (short)f2bf(xb[(size_t)(kk*32 + kg*8 + e)*HW_ + pos]);
      Af[rt][kk] = f;
    }
  }
  #pragma unroll
  for (int ct2 = 0; ct2 < 2; ++ct2) {
    int ot = wv*32 + ct2*16;
    const u16* wr = Wm + ((size_t)(ot + m) << 7) + kg*8;
    short8 Bf[4];
    #pragma unroll
    for (int kk = 0; kk < 4; ++kk)
      Bf[kk] = *(const short8*)(wr + kk*32);
    f32x4 acc[4];
    #pragma unroll
    for (int rt = 0; rt < 4; ++rt) acc[rt] = (f32x4){0.f,0.f,0.f,0.f};
    #pragma unroll
    for (int rt = 0; rt < 4; ++rt)
      #pragma unroll
      for (int kk = 0; kk < 4; ++kk)
        acc[rt] = __builtin_amdgcn_mfma_f32_16x16x32_bf16(Af[rt][kk], Bf[kk], acc[rt], 0, 0, 0);
    #pragma unroll
    for (int rt = 0; rt < 4; ++rt) {
      #pragma unroll
      for (int r = 0; r < 4; ++r)
        st[(rt*16 + kg*4 + r)*136 + ot + m] = f2bf(acc[rt][r]);
    }
  }
  __syncthreads();
  #pragma unroll
  for (int i = 0; i < 4; ++i) {
    int slot = i*256 + t;
    int row = slot >> 4, j = slot & 15;
    short8 v = *(const short8*)(st + row*136 + (j << 3));
    *(short8*)(Out + ((size_t)(pt + row) << 7) + (j << 3)) = v;
  }
}

// MFMA NT GEMM, O=128, LDS-staged coalesced output.
// GN1APPLY: apply GroupNorm1+SiLU to A elements on load (X = xp_raw).
template<int BIAS, int SIG, int GN1APPLY>
__global__ __launch_bounds__(256) void mfma_nt128(const u16* __restrict__ X,
    const u16* __restrict__ Wm, const float* __restrict__ bias, u16* __restrict__ Out,
    const float* __restrict__ stats, const float* __restrict__ gamma,
    const float* __restrict__ beta)
{
  __shared__ __align__(16) u16 st[64*136];
  int t = threadIdx.x;
  int wv = t >> 6, lane = t & 63;
  int m = lane & 15, kg = lane >> 4;
  int pt = blockIdx.x << 6;

  float ga[4][8], bb[4][8];
  if (GN1APPLY) {
    int b = blockIdx.x >> 8;
    const float cnt = (float)(CPG*HW_);
    #pragma unroll
    for (int kk = 0; kk < 4; ++kk) {
      int g = kk*4 + kg;
      float mu = stats[b*16+g]/cnt;
      float var = stats[64+b*16+g]/cnt - mu*mu;
      float rs = rsqrtf(var + 1e-5f);
      #pragma unroll
      for (int e = 0; e < 8; ++e) {
        int ch = kk*32 + kg*8 + e;
        float gm = gamma[ch] * rs;
        ga[kk][e] = gm;
        bb[kk][e] = beta[ch] - mu*gm;
      }
    }
  }

  short8 Af[4][4];
  #pragma unroll
  for (int rt = 0; rt < 4; ++rt) {
    const u16* ar = X + ((size_t)(pt + rt*16 + m) << 7) + kg*8;
    #pragma unroll
    for (int kk = 0; kk < 4; ++kk) {
      short8 v = *(const short8*)(ar + kk*32);
      if (GN1APPLY) {
        short8 o;
        #pragma unroll
        for (int e = 0; e < 8; ++e)
          o[e] = (short)f2bf(siluf_(b2f((u16)v[e])*ga[kk][e] + bb[kk][e]));
        Af[rt][kk] = o;
      } else {
        Af[rt][kk] = v;
      }
    }
  }
  #pragma unroll
  for (int ct2 = 0; ct2 < 2; ++ct2) {
    int ot = wv*32 + ct2*16;
    const u16* wr = Wm + ((size_t)(ot + m) << 7) + kg*8;
    short8 Bf[4];
    #pragma unroll
    for (int kk = 0; kk < 4; ++kk)
      Bf[kk] = *(const short8*)(wr + kk*32);
    f32x4 acc[4];
    #pragma unroll
    for (int rt = 0; rt < 4; ++rt) acc[rt] = (f32x4){0.f,0.f,0.f,0.f};
    #pragma unroll
    for (int rt = 0; rt < 4; ++rt)
      #pragma unroll
      for (int kk = 0; kk < 4; ++kk)
        acc[rt] = __builtin_amdgcn_mfma_f32_16x16x32_bf16(Af[rt][kk], Bf[kk], acc[rt], 0, 0, 0);
    float bv = BIAS ? bias[ot + m] : 0.f;
    #pragma unroll
    for (int rt = 0; rt < 4; ++rt) {
      #pragma unroll
      for (int r = 0; r < 4; ++r) {
        float v = acc[rt][r] + bv;
        if (SIG) v = sigmoidf_(v);
        st[(rt*16 + kg*4 + r)*136 + ot + m] = f2bf(v);
      }
    }
  }
  __syncthreads();
  #pragma unroll
  for (int i = 0; i < 4; ++i) {
    int slot = i*256 + t;
    int row = slot >> 4, j = slot & 15;
    short8 v = *(const short8*)(st + row*136 + (j << 3));
    *(short8*)(Out + ((size_t)(pt + row) << 7) + (j << 3)) = v;
  }
}

// Produce 16-pos coeff chunk (8 tiles, this wave's dir) into cs double buffer.
#define PRODUCE8(chunkv, bufv)  do { \
  int posg_ = (chunkv)*16 + m; int swp_ = (posg_ & 7) << 4; \
  short8 Bfr[4]; \
  _Pragma("unroll") for (int kk = 0; kk < 4; ++kk) \
    Bfr[kk] = *(const short8*)((char*)xs + posg_*256 + (((kk<<6)+(kg<<4)) ^ swp_)); \
  _Pragma("unroll") for (int ti = 0; ti < 8; ++ti) { \
    f32x4 acc = (f32x4){0.f,0.f,0.f,0.f}; \
    _Pragma("unroll") for (int kk = 0; kk < 4; ++kk) \
      acc = __builtin_amdgcn_mfma_f32_16x16x32_bf16(Af[ti][kk], Bfr[kk], acc, 0, 0, 0); \
    int colL_ = (tbase + ti)*16 + (kg<<2); \
    unsigned lo_ = (unsigned)f2bf(acc[0]) | ((unsigned)f2bf(acc[1])<<16); \
    unsigned hi_ = (unsigned)f2bf(acc[2]) | ((unsigned)f2bf(acc[3])<<16); \
    int byte_ = (((bufv)*2 + dw)<<14) + (m<<10) + ((colL_<<1) ^ ((m&7)<<4)); \
    *(uint2*)((char*)cs + byte_) = make_uint2(lo_, hi_); \
  } } while(0)

#define SCAN_STEP(s) { \
  float ar = b2f((u16)(cw[s].x & 0xffffu)) + bv.x; \
  float br = b2f((u16)(cw[s].x >> 16)) + bv.y; \
  float cr = b2f((u16)(cw[s].y & 0xffffu)) + bv.z; \
  float dr = b2f((u16)(cw[s].y >> 16)) + bv.w; \
  float aa = sigmoidf_(ar); \
  h = aa*h + br*xf[s]; \
  yv[s] = cr*h + dr*xf[s]; }

// Fused GN1+SiLU staging + coeff-GEMM + bidirectional scan.
// Block = 512 thr / 8 waves, __launch_bounds__(512,2) -> 256-VGPR budget.
// UNIFORM produce: every wave owns 8 W-tiles (dir = wv&1, tbase = (wv>>1)*8);
// waves 0-3 additionally scan (wv0,1 = fwd ch lo/hi; wv2,3 = rev). All barriers
// in uniform control flow. Reads xp_raw (xpr) + stats and applies GN1+SiLU
// during LDS staging. AXISW=1: lines along W, PART=0 store. AXISW=0: H, PART=1 RMW.
template<int AXISW, int PART>
__global__ __launch_bounds__(512, 2) void scan_fused(const u16* __restrict__ xpr,
    const u16* __restrict__ Wf, const float* __restrict__ bias,
    const float* __restrict__ stats, const float* __restrict__ gamma,
    const float* __restrict__ beta, u16* __restrict__ fusedP)
{
  __shared__ __align__(16) u16 xs[128*128];      // 32 KB, swizzled byte ^ ((pos&7)<<4)
  __shared__ __align__(16) u16 cs[2][2][16*512]; // 64 KB: [buf][dir][16 pos][512 cols]
  __shared__ __align__(16) u16 ysL[128*128];     // 32 KB bf16 partial y [pos][ch]
  int line = blockIdx.x;
  int b = line >> 7, l = line & 127;
  int t = threadIdx.x;
  int wv = t >> 6, lane = t & 63;
  int m = lane & 15, kg = lane >> 4;
  int dw = wv & 1;                    // produce direction
  int tbase = (wv >> 1) << 3;         // 8 tiles per wave: 0,8,16,24

  // GN1 params for staging: this thread's channel group = t&15 (constant over i)
  {
    int cg = t & 15;
    const float cnt = (float)(CPG*HW_);
    float mu = stats[b*16+cg]/cnt;
    float var = stats[64+b*16+cg]/cnt - mu*mu;
    float rs = rsqrtf(var + 1e-5f);
    float ga[8], bb[8];
    #pragma unroll
    for (int e = 0; e < 8; ++e) {
      float gm = gamma[cg*8+e] * rs;
      ga[e] = gm;
      bb[e] = beta[cg*8+e] - mu*gm;
    }
    // stage xp tile with fused GN1+SiLU (128 pos x 128 ch)
    #pragma unroll
    for (int i = 0; i < 4; ++i) {
      int idx = i*512 + t;
      int pos = idx >> 4, j = idx & 15;
      size_t row = AXISW ? ((size_t)(b<<14) + (l<<7) + pos)
                         : ((size_t)(b<<14) + (pos<<7) + l);
      short8 v = *(const short8*)(xpr + (row<<7) + (j<<3));
      short8 o;
      #pragma unroll
      for (int e = 0; e < 8; ++e)
        o[e] = (short)f2bf(siluf_(b2f((u16)v[e])*ga[e] + bb[e]));
      int byte = pos*256 + ((j*16) ^ ((pos&7)<<4));
      *(short8*)((char*)xs + byte) = o;
    }
  }

  // W fragments: 8 tiles per wave, register-resident under (512,2)
  short8 Af[8][4];
  #pragma unroll
  for (int ti = 0; ti < 8; ++ti)
    #pragma unroll
    for (int kk = 0; kk < 4; ++kk)
      Af[ti][kk] = *(const short8*)(Wf + (size_t)(((dw*32 + tbase + ti)*4 + kk)*64 + lane)*8);

  __syncthreads();                       // xs ready
  PRODUCE8(dw ? 7 : 0, 0);
  __syncthreads();                       // cs[0] ready

  int sd = (wv >> 1) & 1;                // scan dir (waves 0-3)
  int sc = ((wv & 1) << 6) + lane;       // scan channel
  float4 bv = make_float4(0.f, 0.f, 0.f, 0.f);
  if (wv < 4) bv = *(const float4*)(bias + (sd << 9) + (sc << 2));
  float h = 0.f;

  #pragma unroll 1
  for (int k = 0; k < 8; ++k) {
    if (k < 7) PRODUCE8(dw ? (6-k) : (k+1), (k+1)&1);
    if (wv < 4) {
      int chunk = sd ? (7-k) : k;
      int csb = (((k&1)*2 + sd) << 14);
      #pragma unroll
      for (int hh = 0; hh < 2; ++hh) {
        uint2 cw[8]; float xf[8];
        #pragma unroll
        for (int s = 0; s < 8; ++s) {
          int posL = sd ? (15 - (hh*8 + s)) : (hh*8 + s);
          cw[s] = *(const uint2*)((char*)cs + csb + (posL<<10) + ((sc<<3) ^ ((posL&7)<<4)));
          int pos = (chunk<<4) + posL;
          xf[s] = b2f(*(const u16*)((char*)xs + pos*256 + ((sc<<1) ^ ((posL&7)<<4))));
        }
        float yv[8];
        __builtin_amdgcn_s_setprio(1);
        #pragma unroll
        for (int s = 0; s < 8; ++s) SCAN_STEP(s)
        __builtin_amdgcn_s_setprio(0);
        #pragma unroll
        for (int s = 0; s < 8; ++s) {
          int posL = sd ? (15 - (hh*8 + s)) : (hh*8 + s);
          u16* yp = ysL + (((chunk<<4) + posL) << 7) + sc;
          if (k <= 3) *yp = f2bf(0.25f*yv[s]);
          else        *yp = f2bf(b2f(*yp) + 0.25f*yv[s]);
        }
      }
    }
    __syncthreads();
  }

  // cooperative coalesced writeout: 2048 short8 slots
  #pragma unroll
  for (int r = 0; r < 4; ++r) {
    int slot = r*512 + t;
    int pos = slot >> 4, j = slot & 15;
    short8 v = *(const short8*)(ysL + (pos << 7) + (j << 3));
    size_t rowg = AXISW ? ((size_t)(b<<14) + (l<<7) + pos)
                        : ((size_t)(b<<14) + (pos<<7) + l);
    u16* op = fusedP + (rowg << 7) + (j << 3);
    if (PART) {
      short8 o = *(const short8*)op;
      short8 rr;
      #pragma unroll
      for (int i = 0; i < 8; ++i) rr[i] = (short)f2bf(b2f((u16)v[i]) + b2f((u16)o[i]));
      *(short8*)op = rr;
    } else {
      *(short8*)op = v;
    }
  }
}

// GroupNorm stats over bf16 channels-last, coalesced short8 loads.
__global__ __launch_bounds__(256) void gn_stats_bf(const u16* __restrict__ X,
    float* __restrict__ stats)
{
  int b = blockIdx.x, chunk = blockIdx.y;
  const u16* base = X + ((size_t)b << 21) + ((size_t)chunk << 15);
  int t = threadIdx.x;
  float s = 0.f, q = 0.f;
  #pragma unroll 4
  for (int it = 0; it < 16; ++it) {
    short8 v = *(const short8*)(base + it*2048 + t*8);
    #pragma unroll
    for (int e = 0; e < 8; ++e) { float f = b2f((u16)v[e]); s += f; q += f*f; }
  }
  s += __shfl_xor(s, 16); q += __shfl_xor(q, 16);
  s += __shfl_xor(s, 32); q += __shfl_xor(q, 32);
  __shared__ float sg[32];
  if (t < 32) sg[t] = 0.f;
  __syncthreads();
  int lane = t & 63;
  if (lane < 16) { atomicAdd(&sg[lane], s); atomicAdd(&sg[16 + lane], q); }
  __syncthreads();
  if (t < 16) atomicAdd(&stats[b*16 + t], sg[t]);
  else if (t < 32) atomicAdd(&stats[64 + b*16 + (t - 16)], sg[t]);
}

// Depthwise 3x3 with fused gate multiply: z = dw3x3(fused * gate), bf16 in/out.
__global__ __launch_bounds__(256) void dwconv(const u16* __restrict__ Z,
    const u16* __restrict__ G, const float* __restrict__ K9, u16* __restrict__ Outp)
{
  __shared__ float kk[1152];
  int t = threadIdx.x;
  for (int i = t; i < 1152; i += 256) kk[i] = K9[i];
  __syncthreads();
  int i4 = blockIdx.x*256 + t;
  size_t base = (size_t)i4 << 2;
  int c0 = (int)(base & 127);
  size_t p = base >> 7;
  int w = (int)(p & 127), h = (int)((p >> 7) & 127), b = (int)(p >> 14);
  float4 acc = make_float4(0.f,0.f,0.f,0.f);
  #pragma unroll
  for (int di = 0; di < 3; ++di) {
    int hy = h + di - 1;
    if ((unsigned)hy > 127u) continue;
    #pragma unroll
    for (int dj = 0; dj < 3; ++dj) {
      int wx = w + dj - 1;
      if ((unsigned)wx > 127u) continue;
      size_t p2 = ((size_t)b << 14) + (hy << 7) + wx;
      ushort4 zv = *(const ushort4*)(Z + (p2 << 7) + c0);
      ushort4 gv = *(const ushort4*)(G + (p2 << 7) + c0);
      int o = di*3 + dj;
      acc.x += b2f(zv.x) * b2f(gv.x) * kk[c0*9 + o];
      acc.y += b2f(zv.y) * b2f(gv.y) * kk[(c0+1)*9 + o];
      acc.z += b2f(zv.z) * b2f(gv.z) * kk[(c0+2)*9 + o];
      acc.w += b2f(zv.w) * b2f(gv.w) * kk[(c0+3)*9 + o];
    }
  }
  ushort4 ov;
  ov.x = f2bf(acc.x); ov.y = f2bf(acc.y); ov.z = f2bf(acc.z); ov.w = f2bf(acc.w);
  *(ushort4*)(Outp + base) = ov;
}

// GN2 apply + SiLU + transpose to channels-first fp32 output. Input bf16.
__global__ __launch_bounds__(256) void gn_final(const u16* __restrict__ Z,
    const float* __restrict__ stats, const float* __restrict__ gamma,
    const float* __restrict__ beta, float* __restrict__ out)
{
  __shared__ float ls[32][129];
  int w0 = blockIdx.x << 5, hh = blockIdx.y, b = blockIdx.z;
  size_t p0 = ((size_t)b << 14) + (hh << 7) + w0;
  int t = threadIdx.x;
  const float cnt = (float)(CPG*HW_);
  #pragma unroll
  for (int i = 0; i < 4; ++i) {
    int l = t + i*256;
    int row = l >> 5, c4 = (l & 31) << 2;
    ushort4 v = *(const ushort4*)(Z + ((p0 + row) << 7) + c4);
    int g = c4 >> 3;
    float mu = stats[b*16+g]/cnt;
    float var = stats[64+b*16+g]/cnt - mu*mu;
    float rs = rsqrtf(var + 1e-5f);
    float vals[4] = {b2f(v.x), b2f(v.y), b2f(v.z), b2f(v.w)};
    #pragma unroll
    for (int j = 0; j < 4; ++j) {
      float nv = (vals[j]-mu)*rs*gamma[c4+j] + beta[c4+j];
      ls[row][c4+j] = siluf_(nv);
    }
  }
  __syncthreads();
  int ww = t & 31, c0 = t >> 5;
  #pragma unroll
  for (int cc = c0; cc < 128; cc += 8) {
    out[(((size_t)(b*128 + cc)) << 14) + (hh << 7) + (w0 + ww)] = ls[ww][cc];
  }
}

extern "C" void kernel_launch(void* const* d_in, const int* in_sizes, int n_in,
                              void* d_out, int out_size, void* d_ws, size_t ws_size,
                              hipStream_t stream)
{
  (void)in_sizes; (void)n_in; (void)out_size; (void)ws_size;
  const float* x      = (const float*)d_in[0];
  const float* w_in   = (const float*)d_in[1];
  const float* g1g    = (const float*)d_in[2];
  const float* g1b    = (const float*)d_in[3];
  const float* w_gate = (const float*)d_in[4];
  const float* b_gate = (const float*)d_in[5];
  const float* dyn_w  = (const float*)d_in[6];
  const float* dyn_b  = (const float*)d_in[7];
  const float* dwk    = (const float*)d_in[8];
  const float* w_out  = (const float*)d_in[9];
  const float* g2g    = (const float*)d_in[10];
  const float* g2b    = (const float*)d_in[11];
  float* out = (float*)d_out;

  char* p = (char*)d_ws;
  u16*   Zbuf   = (u16*)p;              p += (size_t)S_*2;   // scratch for Zdw
  u16*   xpr    = (u16*)p;              p += (size_t)S_*2;   // xp_raw bf16; later Zout
  u16*   fusedP = (u16*)p;              p += (size_t)S_*2;   // fused partial/final bf16
  u16*   Gbf    = (u16*)p;              p += (size_t)S_*2;   // gate bf16
  u16*   wfrag  = (u16*)p;              p += (size_t)262144*2;
  u16*   wgbf   = (u16*)p;              p += (size_t)16384*2;
  u16*   wobf   = (u16*)p;              p += (size_t)16384*2;
  u16*   wibf   = (u16*)p;              p += (size_t)16384*2;
  float* bperm  = (float*)p;            p += (size_t)2048*4;
  float* stats  = (float*)p;            p += (size_t)256*4;
  u16*   Zdw    = Zbuf;
  u16*   Zout   = xpr;                  // alias (xp_raw dead after gate GEMM + scans)

  prep_kernel<<<1225, 256, 0, stream>>>(dyn_w, dyn_b, w_gate, w_out, w_in,
                                        wfrag, bperm, wgbf, wobf, wibf, stats);
  mfma_inproj<<<1024, 256, 0, stream>>>(x, wibf, xpr);
  gn_stats_bf<<<dim3(4, 64), 256, 0, stream>>>(xpr, stats);

  scan_fused<1,0><<<512, 512, 0, stream>>>(xpr, wfrag, bperm, stats, g1g, g1b, fusedP);
  scan_fused<0,1><<<512, 512, 0, stream>>>(xpr, wfrag + 2*65536, bperm + 1024, stats, g1g, g1b, fusedP);

  mfma_nt128<1,1,1><<<1024, 256, 0, stream>>>(xpr, wgbf, b_gate, Gbf, stats, g1g, g1b);
  dwconv<<<8192, 256, 0, stream>>>(fusedP, Gbf, dwk, Zdw);
  mfma_nt128<0,0,0><<<1024, 256, 0, stream>>>(Zdw, wobf, nullptr, Zout, nullptr, nullptr, nullptr);
  gn_stats_bf<<<dim3(4, 64), 256, 0, stream>>>(Zout, stats + 128);
  gn_final<<<dim3(4, 128, 4), 256, 0, stream>>>(Zout, stats + 128, g2g, g2b, out);
}

// Round 13
// 214.293 us; speedup vs baseline: 1.4775x; 1.1107x over previous
//
#include <hip/hip_runtime.h>
#include <math.h>

#define B_ 4
#define C_ 128
#define HW_ 16384
#define P_ 65536
#define S_ 8388608   // B*C*H*W elements
#define CPG 8        // channels per group (128/16)

typedef unsigned short u16;
typedef __attribute__((ext_vector_type(8))) short short8;
typedef __attribute__((ext_vector_type(4))) float f32x4;

__device__ __forceinline__ float sigmoidf_(float x){ return 1.f/(1.f+__expf(-x)); }
__device__ __forceinline__ float siluf_(float x){ return x*sigmoidf_(x); }
__device__ __forceinline__ u16 f2bf(float f){
  unsigned x = __float_as_uint(f);
  return (u16)((x + 0x7fffu + ((x >> 16) & 1u)) >> 16);
}
__device__ __forceinline__ float b2f(u16 u){ return __uint_as_float(((unsigned)u) << 16); }

// Build wfrag (dyn_w in MFMA A-fragment order), bperm, wgbf, wobf, wibf, stats=0.
__global__ __launch_bounds__(256) void prep_kernel(const float* __restrict__ dyn_w,
    const float* __restrict__ dyn_b, const float* __restrict__ w_gate,
    const float* __restrict__ w_out, const float* __restrict__ w_in,
    u16* __restrict__ wfrag, float* __restrict__ bperm, u16* __restrict__ wgbf,
    u16* __restrict__ wobf, u16* __restrict__ wibf, float* __restrict__ stats)
{
  int idx = blockIdx.x*256 + threadIdx.x;
  if (idx < 262144) {
    int e = idx & 7, lane = (idx >> 3) & 63, kk = (idx >> 9) & 3;
    int ct = (idx >> 11) & 31, d = idx >> 16;
    int m = lane & 15, kg = lane >> 4;
    int col = ct*16 + m;
    int c = col >> 2, f = col & 3;
    int k = kk*32 + kg*8 + e;
    wfrag[idx] = f2bf(dyn_w[(size_t)((d*512) + f*128 + c)*128 + k]);
  } else if (idx < 264192) {
    int i2 = idx - 262144;
    int op = i2 & 511, d = i2 >> 9;
    bperm[i2] = dyn_b[d*512 + (op & 3)*128 + (op >> 2)];
  } else if (idx < 280576) {
    wgbf[idx - 264192] = f2bf(w_gate[idx - 264192]);
  } else if (idx < 296960) {
    wobf[idx - 280576] = f2bf(w_out[idx - 280576]);
  } else if (idx < 313344) {
    wibf[idx - 296960] = f2bf(w_in[idx - 296960]);
  } else if (idx < 313600) {
    stats[idx - 313344] = 0.f;
  }
}

// in_proj MFMA GEMM reading channels-first fp32 x directly.
__global__ __launch_bounds__(256) void mfma_inproj(const float* __restrict__ x,
    const u16* __restrict__ Wm, u16* __restrict__ Out)
{
  __shared__ __align__(16) u16 st[64*136];
  int t = threadIdx.x;
  int wv = t >> 6, lane = t & 63;
  int m = lane & 15, kg = lane >> 4;
  int pt = blockIdx.x << 6;
  int b = blockIdx.x >> 8;
  int hw0 = (blockIdx.x & 255) << 6;
  const float* xb = x + ((size_t)b << 21);

  short8 Af[4][4];
  #pragma unroll
  for (int rt = 0; rt < 4; ++rt) {
    int pos = hw0 + rt*16 + m;
    #pragma unroll
    for (int kk = 0; kk < 4; ++kk) {
      short8 f;
      #pragma unroll
      for (int e = 0; e < 8; ++e)
        f[e] = (short)f2bf(xb[(size_t)(kk*32 + kg*8 + e)*HW_ + pos]);
      Af[rt][kk] = f;
    }
  }
  #pragma unroll
  for (int ct2 = 0; ct2 < 2; ++ct2) {
    int ot = wv*32 + ct2*16;
    const u16* wr = Wm + ((size_t)(ot + m) << 7) + kg*8;
    short8 Bf[4];
    #pragma unroll
    for (int kk = 0; kk < 4; ++kk)
      Bf[kk] = *(const short8*)(wr + kk*32);
    f32x4 acc[4];
    #pragma unroll
    for (int rt = 0; rt < 4; ++rt) acc[rt] = (f32x4){0.f,0.f,0.f,0.f};
    #pragma unroll
    for (int rt = 0; rt < 4; ++rt)
      #pragma unroll
      for (int kk = 0; kk < 4; ++kk)
        acc[rt] = __builtin_amdgcn_mfma_f32_16x16x32_bf16(Af[rt][kk], Bf[kk], acc[rt], 0, 0, 0);
    #pragma unroll
    for (int rt = 0; rt < 4; ++rt) {
      #pragma unroll
      for (int r = 0; r < 4; ++r)
        st[(rt*16 + kg*4 + r)*136 + ot + m] = f2bf(acc[rt][r]);
    }
  }
  __syncthreads();
  #pragma unroll
  for (int i = 0; i < 4; ++i) {
    int slot = i*256 + t;
    int row = slot >> 4, j = slot & 15;
    short8 v = *(const short8*)(st + row*136 + (j << 3));
    *(short8*)(Out + ((size_t)(pt + row) << 7) + (j << 3)) = v;
  }
}

// MFMA NT GEMM, O=128, LDS-staged coalesced output.
// GN1APPLY: apply GroupNorm1+SiLU to A elements on load (X = xp_raw).
template<int BIAS, int SIG, int GN1APPLY>
__global__ __launch_bounds__(256) void mfma_nt128(const u16* __restrict__ X,
    const u16* __restrict__ Wm, const float* __restrict__ bias, u16* __restrict__ Out,
    const float* __restrict__ stats, const float* __restrict__ gamma,
    const float* __restrict__ beta)
{
  __shared__ __align__(16) u16 st[64*136];
  int t = threadIdx.x;
  int wv = t >> 6, lane = t & 63;
  int m = lane & 15, kg = lane >> 4;
  int pt = blockIdx.x << 6;

  float ga[4][8], bb[4][8];
  if (GN1APPLY) {
    int b = blockIdx.x >> 8;
    const float cnt = (float)(CPG*HW_);
    #pragma unroll
    for (int kk = 0; kk < 4; ++kk) {
      int g = kk*4 + kg;
      float mu = stats[b*16+g]/cnt;
      float var = stats[64+b*16+g]/cnt - mu*mu;
      float rs = rsqrtf(var + 1e-5f);
      #pragma unroll
      for (int e = 0; e < 8; ++e) {
        int ch = kk*32 + kg*8 + e;
        float gm = gamma[ch] * rs;
        ga[kk][e] = gm;
        bb[kk][e] = beta[ch] - mu*gm;
      }
    }
  }

  short8 Af[4][4];
  #pragma unroll
  for (int rt = 0; rt < 4; ++rt) {
    const u16* ar = X + ((size_t)(pt + rt*16 + m) << 7) + kg*8;
    #pragma unroll
    for (int kk = 0; kk < 4; ++kk) {
      short8 v = *(const short8*)(ar + kk*32);
      if (GN1APPLY) {
        short8 o;
        #pragma unroll
        for (int e = 0; e < 8; ++e)
          o[e] = (short)f2bf(siluf_(b2f((u16)v[e])*ga[kk][e] + bb[kk][e]));
        Af[rt][kk] = o;
      } else {
        Af[rt][kk] = v;
      }
    }
  }
  #pragma unroll
  for (int ct2 = 0; ct2 < 2; ++ct2) {
    int ot = wv*32 + ct2*16;
    const u16* wr = Wm + ((size_t)(ot + m) << 7) + kg*8;
    short8 Bf[4];
    #pragma unroll
    for (int kk = 0; kk < 4; ++kk)
      Bf[kk] = *(const short8*)(wr + kk*32);
    f32x4 acc[4];
    #pragma unroll
    for (int rt = 0; rt < 4; ++rt) acc[rt] = (f32x4){0.f,0.f,0.f,0.f};
    #pragma unroll
    for (int rt = 0; rt < 4; ++rt)
      #pragma unroll
      for (int kk = 0; kk < 4; ++kk)
        acc[rt] = __builtin_amdgcn_mfma_f32_16x16x32_bf16(Af[rt][kk], Bf[kk], acc[rt], 0, 0, 0);
    float bv = BIAS ? bias[ot + m] : 0.f;
    #pragma unroll
    for (int rt = 0; rt < 4; ++rt) {
      #pragma unroll
      for (int r = 0; r < 4; ++r) {
        float v = acc[rt][r] + bv;
        if (SIG) v = sigmoidf_(v);
        st[(rt*16 + kg*4 + r)*136 + ot + m] = f2bf(v);
      }
    }
  }
  __syncthreads();
  #pragma unroll
  for (int i = 0; i < 4; ++i) {
    int slot = i*256 + t;
    int row = slot >> 4, j = slot & 15;
    short8 v = *(const short8*)(st + row*136 + (j << 3));
    *(short8*)(Out + ((size_t)(pt + row) << 7) + (j << 3)) = v;
  }
}

// Produce 16-pos coeff chunk into cs double buffer (bank-swizzled).
#define PRODUCE(NT, bufv, chunkv)  do { \
  int posg_ = (chunkv)*16 + m; int swp_ = (posg_ & 7) << 4; \
  short8 Bfr[4]; \
  _Pragma("unroll") for (int kk = 0; kk < 4; ++kk) \
    Bfr[kk] = *(const short8*)((char*)xs + posg_*256 + (((kk<<6)+(kg<<4)) ^ swp_)); \
  _Pragma("unroll") for (int ti = 0; ti < NT; ++ti) { \
    f32x4 acc = (f32x4){0.f,0.f,0.f,0.f}; \
    _Pragma("unroll") for (int kk = 0; kk < 4; ++kk) \
      acc = __builtin_amdgcn_mfma_f32_16x16x32_bf16(Af[ti][kk], Bfr[kk], acc, 0, 0, 0); \
    int colL_ = (tbase + ti)*16 + (kg<<2); \
    unsigned lo_ = (unsigned)f2bf(acc[0]) | ((unsigned)f2bf(acc[1])<<16); \
    unsigned hi_ = (unsigned)f2bf(acc[2]) | ((unsigned)f2bf(acc[3])<<16); \
    int byte_ = (((bufv)*2 + dw)<<14) + (m<<10) + ((colL_<<1) ^ ((m&7)<<4)); \
    *(uint2*)((char*)cs + byte_) = make_uint2(lo_, hi_); \
  } } while(0)

#define SCAN_STEP(s) { \
  float ar = b2f((u16)(cw[s].x & 0xffffu)) + bv.x; \
  float br = b2f((u16)(cw[s].x >> 16)) + bv.y; \
  float cr = b2f((u16)(cw[s].y & 0xffffu)) + bv.z; \
  float dr = b2f((u16)(cw[s].y >> 16)) + bv.w; \
  float aa = sigmoidf_(ar); \
  h = aa*h + br*xf[s]; \
  yv[s] = cr*h + dr*xf[s]; }

// Fused GN1+SiLU staging + coeff-GEMM + bidirectional scan (r9-proven structure).
// Block = 512 thr (8 waves): waves 0-3 = scanners (+4 W-tiles, resident); waves
// 4-7 = producers (12 W-tiles, compiler refetches from L2). cs double-buffered,
// y accumulated in LDS. Reads xp_raw + GN1 stats; applies GN1+SiLU at staging.
template<int AXISW, int PART>
__global__ __launch_bounds__(512, 2) void scan_fused(const u16* __restrict__ xpr,
    const u16* __restrict__ Wf, const float* __restrict__ bias,
    const float* __restrict__ stats, const float* __restrict__ gamma,
    const float* __restrict__ beta, u16* __restrict__ fusedP)
{
  __shared__ __align__(16) u16 xs[128*128];      // 32 KB, swizzled byte ^ ((pos&7)<<4)
  __shared__ __align__(16) u16 cs[2][2][16*512]; // 64 KB: [buf][dir][16 pos][512 cols]
  __shared__ __align__(16) u16 ysL[128*128];     // 32 KB bf16 partial y [pos][ch]
  int line = blockIdx.x;
  int b = line >> 7, l = line & 127;
  int t = threadIdx.x;
  int wv = t >> 6, lane = t & 63;
  int m = lane & 15, kg = lane >> 4;
  int dw = (wv >> 1) & 1;    // this wave's coeff direction

  // stage xp tile with fused GN1+SiLU (ga/bb scoped: dead before Af loads)
  {
    int cg = t & 15;
    const float cnt = (float)(CPG*HW_);
    float mu = stats[b*16+cg]/cnt;
    float var = stats[64+b*16+cg]/cnt - mu*mu;
    float rs = rsqrtf(var + 1e-5f);
    float ga[8], bb[8];
    #pragma unroll
    for (int e = 0; e < 8; ++e) {
      float gm = gamma[cg*8+e] * rs;
      ga[e] = gm;
      bb[e] = beta[cg*8+e] - mu*gm;
    }
    #pragma unroll
    for (int i = 0; i < 4; ++i) {
      int idx = i*512 + t;
      int pos = idx >> 4, j = idx & 15;
      size_t row = AXISW ? ((size_t)(b<<14) + (l<<7) + pos)
                         : ((size_t)(b<<14) + (pos<<7) + l);
      short8 v = *(const short8*)(xpr + (row<<7) + (j<<3));
      short8 o;
      #pragma unroll
      for (int e = 0; e < 8; ++e)
        o[e] = (short)f2bf(siluf_(b2f((u16)v[e])*ga[e] + bb[e]));
      int byte = pos*256 + ((j*16) ^ ((pos&7)<<4));
      *(short8*)((char*)xs + byte) = o;
    }
  }

  if (wv < 4) {
    // ---------- scanner + light producer ----------
    int tbase = (wv & 1) * 4;
    short8 Af[4][4];
    #pragma unroll
    for (int ti = 0; ti < 4; ++ti)
      #pragma unroll
      for (int kk = 0; kk < 4; ++kk)
        Af[ti][kk] = *(const short8*)(Wf + (size_t)(((dw*32 + tbase + ti)*4 + kk)*64 + lane)*8);
    __syncthreads();                       // xs ready
    PRODUCE(4, 0, dw ? 7 : 0);
    __syncthreads();                       // cs[0] ready

    int sd = dw;
    int sc = ((wv & 1) << 6) + lane;       // scan channel 0..127
    float4 bv = *(const float4*)(bias + (sd << 9) + (sc << 2));
    float h = 0.f;

    #pragma unroll 1
    for (int k = 0; k < 8; ++k) {
      if (k < 7) PRODUCE(4, (k+1)&1, dw ? (6-k) : (k+1));
      int chunk = sd ? (7-k) : k;
      int csb = (((k&1)*2 + sd) << 14);
      uint2 cw[16];
      #pragma unroll
      for (int s = 0; s < 16; ++s)
        cw[s] = *(const uint2*)((char*)cs + csb + (s<<10) + ((sc<<3) ^ ((s&7)<<4)));
      float xf[16];
      #pragma unroll
      for (int s = 0; s < 16; ++s) {
        int pos = (chunk<<4) + s;
        xf[s] = b2f(*(const u16*)((char*)xs + pos*256 + ((sc<<1) ^ ((s&7)<<4))));
      }
      float yv[16];
      __builtin_amdgcn_s_setprio(1);
      if (sd == 0) {
        #pragma unroll
        for (int s = 0; s < 16; ++s) SCAN_STEP(s)
      } else {
        #pragma unroll
        for (int s = 15; s >= 0; --s) SCAN_STEP(s)
      }
      __builtin_amdgcn_s_setprio(0);
      u16* yrow = ysL + (chunk << 11) + sc;
      if (k <= 3) {
        #pragma unroll
        for (int s = 0; s < 16; ++s) yrow[s << 7] = f2bf(0.25f*yv[s]);
      } else {
        #pragma unroll
        for (int s = 0; s < 16; ++s) {
          float o = b2f(yrow[s << 7]);
          yrow[s << 7] = f2bf(o + 0.25f*yv[s]);
        }
      }
      __syncthreads();
    }
  } else {
    // ---------- heavy producer ----------
    int tbase = 8 + (wv & 1) * 12;
    short8 Af[12][4];
    #pragma unroll
    for (int ti = 0; ti < 12; ++ti)
      #pragma unroll
      for (int kk = 0; kk < 4; ++kk)
        Af[ti][kk] = *(const short8*)(Wf + (size_t)(((dw*32 + tbase + ti)*4 + kk)*64 + lane)*8);
    __syncthreads();                       // xs ready
    PRODUCE(12, 0, dw ? 7 : 0);
    __syncthreads();                       // cs[0] ready
    #pragma unroll 1
    for (int k = 0; k < 8; ++k) {
      if (k < 7) PRODUCE(12, (k+1)&1, dw ? (6-k) : (k+1));
      __syncthreads();
    }
  }

  // cooperative coalesced writeout: 2048 short8 slots
  #pragma unroll
  for (int r = 0; r < 4; ++r) {
    int slot = r*512 + t;
    int pos = slot >> 4, j = slot & 15;
    short8 v = *(const short8*)(ysL + (pos << 7) + (j << 3));
    size_t rowg = AXISW ? ((size_t)(b<<14) + (l<<7) + pos)
                        : ((size_t)(b<<14) + (pos<<7) + l);
    u16* op = fusedP + (rowg << 7) + (j << 3);
    if (PART) {
      short8 o = *(const short8*)op;
      short8 rr;
      #pragma unroll
      for (int i = 0; i < 8; ++i) rr[i] = (short)f2bf(b2f((u16)v[i]) + b2f((u16)o[i]));
      *(short8*)op = rr;
    } else {
      *(short8*)op = v;
    }
  }
}

// GroupNorm stats over bf16 channels-last, coalesced short8 loads.
__global__ __launch_bounds__(256) void gn_stats_bf(const u16* __restrict__ X,
    float* __restrict__ stats)
{
  int b = blockIdx.x, chunk = blockIdx.y;
  const u16* base = X + ((size_t)b << 21) + ((size_t)chunk << 15);
  int t = threadIdx.x;
  float s = 0.f, q = 0.f;
  #pragma unroll 4
  for (int it = 0; it < 16; ++it) {
    short8 v = *(const short8*)(base + it*2048 + t*8);
    #pragma unroll
    for (int e = 0; e < 8; ++e) { float f = b2f((u16)v[e]); s += f; q += f*f; }
  }
  s += __shfl_xor(s, 16); q += __shfl_xor(q, 16);
  s += __shfl_xor(s, 32); q += __shfl_xor(q, 32);
  __shared__ float sg[32];
  if (t < 32) sg[t] = 0.f;
  __syncthreads();
  int lane = t & 63;
  if (lane < 16) { atomicAdd(&sg[lane], s); atomicAdd(&sg[16 + lane], q); }
  __syncthreads();
  if (t < 16) atomicAdd(&stats[b*16 + t], sg[t]);
  else if (t < 32) atomicAdd(&stats[64 + b*16 + (t - 16)], sg[t]);
}

// Depthwise 3x3 with fused gate multiply: z = dw3x3(fused * gate), bf16 in/out.
__global__ __launch_bounds__(256) void dwconv(const u16* __restrict__ Z,
    const u16* __restrict__ G, const float* __restrict__ K9, u16* __restrict__ Outp)
{
  __shared__ float kk[1152];
  int t = threadIdx.x;
  for (int i = t; i < 1152; i += 256) kk[i] = K9[i];
  __syncthreads();
  int i4 = blockIdx.x*256 + t;
  size_t base = (size_t)i4 << 2;
  int c0 = (int)(base & 127);
  size_t p = base >> 7;
  int w = (int)(p & 127), h = (int)((p >> 7) & 127), b = (int)(p >> 14);
  float4 acc = make_float4(0.f,0.f,0.f,0.f);
  #pragma unroll
  for (int di = 0; di < 3; ++di) {
    int hy = h + di - 1;
    if ((unsigned)hy > 127u) continue;
    #pragma unroll
    for (int dj = 0; dj < 3; ++dj) {
      int wx = w + dj - 1;
      if ((unsigned)wx > 127u) continue;
      size_t p2 = ((size_t)b << 14) + (hy << 7) + wx;
      ushort4 zv = *(const ushort4*)(Z + (p2 << 7) + c0);
      ushort4 gv = *(const ushort4*)(G + (p2 << 7) + c0);
      int o = di*3 + dj;
      acc.x += b2f(zv.x) * b2f(gv.x) * kk[c0*9 + o];
      acc.y += b2f(zv.y) * b2f(gv.y) * kk[(c0+1)*9 + o];
      acc.z += b2f(zv.z) * b2f(gv.z) * kk[(c0+2)*9 + o];
      acc.w += b2f(zv.w) * b2f(gv.w) * kk[(c0+3)*9 + o];
    }
  }
  ushort4 ov;
  ov.x = f2bf(acc.x); ov.y = f2bf(acc.y); ov.z = f2bf(acc.z); ov.w = f2bf(acc.w);
  *(ushort4*)(Outp + base) = ov;
}

// GN2 apply + SiLU + transpose to channels-first fp32 output. Input bf16.
__global__ __launch_bounds__(256) void gn_final(const u16* __restrict__ Z,
    const float* __restrict__ stats, const float* __restrict__ gamma,
    const float* __restrict__ beta, float* __restrict__ out)
{
  __shared__ float ls[32][129];
  int w0 = blockIdx.x << 5, hh = blockIdx.y, b = blockIdx.z;
  size_t p0 = ((size_t)b << 14) + (hh << 7) + w0;
  int t = threadIdx.x;
  const float cnt = (float)(CPG*HW_);
  #pragma unroll
  for (int i = 0; i < 4; ++i) {
    int l = t + i*256;
    int row = l >> 5, c4 = (l & 31) << 2;
    ushort4 v = *(const ushort4*)(Z + ((p0 + row) << 7) + c4);
    int g = c4 >> 3;
    float mu = stats[b*16+g]/cnt;
    float var = stats[64+b*16+g]/cnt - mu*mu;
    float rs = rsqrtf(var + 1e-5f);
    float vals[4] = {b2f(v.x), b2f(v.y), b2f(v.z), b2f(v.w)};
    #pragma unroll
    for (int j = 0; j < 4; ++j) {
      float nv = (vals[j]-mu)*rs*gamma[c4+j] + beta[c4+j];
      ls[row][c4+j] = siluf_(nv);
    }
  }
  __syncthreads();
  int ww = t & 31, c0 = t >> 5;
  #pragma unroll
  for (int cc = c0; cc < 128; cc += 8) {
    out[(((size_t)(b*128 + cc)) << 14) + (hh << 7) + (w0 + ww)] = ls[ww][cc];
  }
}

extern "C" void kernel_launch(void* const* d_in, const int* in_sizes, int n_in,
                              void* d_out, int out_size, void* d_ws, size_t ws_size,
                              hipStream_t stream)
{
  (void)in_sizes; (void)n_in; (void)out_size; (void)ws_size;
  const float* x      = (const float*)d_in[0];
  const float* w_in   = (const float*)d_in[1];
  const float* g1g    = (const float*)d_in[2];
  const float* g1b    = (const float*)d_in[3];
  const float* w_gate = (const float*)d_in[4];
  const float* b_gate = (const float*)d_in[5];
  const float* dyn_w  = (const float*)d_in[6];
  const float* dyn_b  = (const float*)d_in[7];
  const float* dwk    = (const float*)d_in[8];
  const float* w_out  = (const float*)d_in[9];
  const float* g2g    = (const float*)d_in[10];
  const float* g2b    = (const float*)d_in[11];
  float* out = (float*)d_out;

  char* p = (char*)d_ws;
  u16*   Zbuf   = (u16*)p;              p += (size_t)S_*2;   // scratch for Zdw
  u16*   xpr    = (u16*)p;              p += (size_t)S_*2;   // xp_raw bf16; later Zout
  u16*   fusedP = (u16*)p;              p += (size_t)S_*2;   // fused partial/final bf16
  u16*   Gbf    = (u16*)p;              p += (size_t)S_*2;   // gate bf16
  u16*   wfrag  = (u16*)p;              p += (size_t)262144*2;
  u16*   wgbf   = (u16*)p;              p += (size_t)16384*2;
  u16*   wobf   = (u16*)p;              p += (size_t)16384*2;
  u16*   wibf   = (u16*)p;              p += (size_t)16384*2;
  float* bperm  = (float*)p;            p += (size_t)2048*4;
  float* stats  = (float*)p;            p += (size_t)256*4;
  u16*   Zdw    = Zbuf;
  u16*   Zout   = xpr;                  // alias (xp_raw dead after gate GEMM + scans)

  prep_kernel<<<1225, 256, 0, stream>>>(dyn_w, dyn_b, w_gate, w_out, w_in,
                                        wfrag, bperm, wgbf, wobf, wibf, stats);
  mfma_inproj<<<1024, 256, 0, stream>>>(x, wibf, xpr);
  gn_stats_bf<<<dim3(4, 64), 256, 0, stream>>>(xpr, stats);

  scan_fused<1,0><<<512, 512, 0, stream>>>(xpr, wfrag, bperm, stats, g1g, g1b, fusedP);
  scan_fused<0,1><<<512, 512, 0, stream>>>(xpr, wfrag + 2*65536, bperm + 1024, stats, g1g, g1b, fusedP);

  mfma_nt128<1,1,1><<<1024, 256, 0, stream>>>(xpr, wgbf, b_gate, Gbf, stats, g1g, g1b);
  dwconv<<<8192, 256, 0, stream>>>(fusedP, Gbf, dwk, Zdw);
  mfma_nt128<0,0,0><<<1024, 256, 0, stream>>>(Zdw, wobf, nullptr, Zout, nullptr, nullptr, nullptr);
  gn_stats_bf<<<dim3(4, 64), 256, 0, stream>>>(Zout, stats + 128);
  gn_final<<<dim3(4, 128, 4), 256, 0, stream>>>(Zout, stats + 128, g2g, g2b, out);
}

// Round 14
// 210.634 us; speedup vs baseline: 1.5032x; 1.0174x over previous
//
#include <hip/hip_runtime.h>
#include <math.h>

#define B_ 4
#define C_ 128
#define HW_ 16384
#define P_ 65536
#define S_ 8388608   // B*C*H*W elements
#define CPG 8        // channels per group (128/16)

typedef unsigned short u16;
typedef __attribute__((ext_vector_type(8))) short short8;
typedef __attribute__((ext_vector_type(4))) float f32x4;

__device__ __forceinline__ float sigmoidf_(float x){ return 1.f/(1.f+__expf(-x)); }
__device__ __forceinline__ float siluf_(float x){ return x*sigmoidf_(x); }
__device__ __forceinline__ u16 f2bf(float f){
  unsigned x = __float_as_uint(f);
  return (u16)((x + 0x7fffu + ((x >> 16) & 1u)) >> 16);
}
__device__ __forceinline__ float b2f(u16 u){ return __uint_as_float(((unsigned)u) << 16); }

// Build wfrag (dyn_w in MFMA A-fragment order), bperm, wgbf, wobf, wibf, stats=0.
__global__ __launch_bounds__(256) void prep_kernel(const float* __restrict__ dyn_w,
    const float* __restrict__ dyn_b, const float* __restrict__ w_gate,
    const float* __restrict__ w_out, const float* __restrict__ w_in,
    u16* __restrict__ wfrag, float* __restrict__ bperm, u16* __restrict__ wgbf,
    u16* __restrict__ wobf, u16* __restrict__ wibf, float* __restrict__ stats)
{
  int idx = blockIdx.x*256 + threadIdx.x;
  if (idx < 262144) {
    int e = idx & 7, lane = (idx >> 3) & 63, kk = (idx >> 9) & 3;
    int ct = (idx >> 11) & 31, d = idx >> 16;
    int m = lane & 15, kg = lane >> 4;
    int col = ct*16 + m;
    int c = col >> 2, f = col & 3;
    int k = kk*32 + kg*8 + e;
    wfrag[idx] = f2bf(dyn_w[(size_t)((d*512) + f*128 + c)*128 + k]);
  } else if (idx < 264192) {
    int i2 = idx - 262144;
    int op = i2 & 511, d = i2 >> 9;
    bperm[i2] = dyn_b[d*512 + (op & 3)*128 + (op >> 2)];
  } else if (idx < 280576) {
    wgbf[idx - 264192] = f2bf(w_gate[idx - 264192]);
  } else if (idx < 296960) {
    wobf[idx - 280576] = f2bf(w_out[idx - 280576]);
  } else if (idx < 313344) {
    wibf[idx - 296960] = f2bf(w_in[idx - 296960]);
  } else if (idx < 313600) {
    stats[idx - 313344] = 0.f;
  }
}

// in_proj MFMA GEMM reading channels-first fp32 x directly.
__global__ __launch_bounds__(256) void mfma_inproj(const float* __restrict__ x,
    const u16* __restrict__ Wm, u16* __restrict__ Out)
{
  __shared__ __align__(16) u16 st[64*136];
  int t = threadIdx.x;
  int wv = t >> 6, lane = t & 63;
  int m = lane & 15, kg = lane >> 4;
  int pt = blockIdx.x << 6;
  int b = blockIdx.x >> 8;
  int hw0 = (blockIdx.x & 255) << 6;
  const float* xb = x + ((size_t)b << 21);

  short8 Af[4][4];
  #pragma unroll
  for (int rt = 0; rt < 4; ++rt) {
    int pos = hw0 + rt*16 + m;
    #pragma unroll
    for (int kk = 0; kk < 4; ++kk) {
      short8 f;
      #pragma unroll
      for (int e = 0; e < 8; ++e)
        f[e] = (short)f2bf(xb[(size_t)(kk*32 + kg*8 + e)*HW_ + pos]);
      Af[rt][kk] = f;
    }
  }
  #pragma unroll
  for (int ct2 = 0; ct2 < 2; ++ct2) {
    int ot = wv*32 + ct2*16;
    const u16* wr = Wm + ((size_t)(ot + m) << 7) + kg*8;
    short8 Bf[4];
    #pragma unroll
    for (int kk = 0; kk < 4; ++kk)
      Bf[kk] = *(const short8*)(wr + kk*32);
    f32x4 acc[4];
    #pragma unroll
    for (int rt = 0; rt < 4; ++rt) acc[rt] = (f32x4){0.f,0.f,0.f,0.f};
    #pragma unroll
    for (int rt = 0; rt < 4; ++rt)
      #pragma unroll
      for (int kk = 0; kk < 4; ++kk)
        acc[rt] = __builtin_amdgcn_mfma_f32_16x16x32_bf16(Af[rt][kk], Bf[kk], acc[rt], 0, 0, 0);
    #pragma unroll
    for (int rt = 0; rt < 4; ++rt) {
      #pragma unroll
      for (int r = 0; r < 4; ++r)
        st[(rt*16 + kg*4 + r)*136 + ot + m] = f2bf(acc[rt][r]);
    }
  }
  __syncthreads();
  #pragma unroll
  for (int i = 0; i < 4; ++i) {
    int slot = i*256 + t;
    int row = slot >> 4, j = slot & 15;
    short8 v = *(const short8*)(st + row*136 + (j << 3));
    *(short8*)(Out + ((size_t)(pt + row) << 7) + (j << 3)) = v;
  }
}

// MFMA NT GEMM, O=128, LDS-staged coalesced output.
template<int BIAS, int SIG>
__global__ __launch_bounds__(256) void mfma_nt128(const u16* __restrict__ X,
    const u16* __restrict__ Wm, const float* __restrict__ bias, u16* __restrict__ Out)
{
  __shared__ __align__(16) u16 st[64*136];
  int t = threadIdx.x;
  int wv = t >> 6, lane = t & 63;
  int m = lane & 15, kg = lane >> 4;
  int pt = blockIdx.x << 6;

  short8 Af[4][4];
  #pragma unroll
  for (int rt = 0; rt < 4; ++rt) {
    const u16* ar = X + ((size_t)(pt + rt*16 + m) << 7) + kg*8;
    #pragma unroll
    for (int kk = 0; kk < 4; ++kk)
      Af[rt][kk] = *(const short8*)(ar + kk*32);
  }
  #pragma unroll
  for (int ct2 = 0; ct2 < 2; ++ct2) {
    int ot = wv*32 + ct2*16;
    const u16* wr = Wm + ((size_t)(ot + m) << 7) + kg*8;
    short8 Bf[4];
    #pragma unroll
    for (int kk = 0; kk < 4; ++kk)
      Bf[kk] = *(const short8*)(wr + kk*32);
    f32x4 acc[4];
    #pragma unroll
    for (int rt = 0; rt < 4; ++rt) acc[rt] = (f32x4){0.f,0.f,0.f,0.f};
    #pragma unroll
    for (int rt = 0; rt < 4; ++rt)
      #pragma unroll
      for (int kk = 0; kk < 4; ++kk)
        acc[rt] = __builtin_amdgcn_mfma_f32_16x16x32_bf16(Af[rt][kk], Bf[kk], acc[rt], 0, 0, 0);
    float bv = BIAS ? bias[ot + m] : 0.f;
    #pragma unroll
    for (int rt = 0; rt < 4; ++rt) {
      #pragma unroll
      for (int r = 0; r < 4; ++r) {
        float v = acc[rt][r] + bv;
        if (SIG) v = sigmoidf_(v);
        st[(rt*16 + kg*4 + r)*136 + ot + m] = f2bf(v);
      }
    }
  }
  __syncthreads();
  #pragma unroll
  for (int i = 0; i < 4; ++i) {
    int slot = i*256 + t;
    int row = slot >> 4, j = slot & 15;
    short8 v = *(const short8*)(st + row*136 + (j << 3));
    *(short8*)(Out + ((size_t)(pt + row) << 7) + (j << 3)) = v;
  }
}

// Produce 16-pos coeff chunk (4 tiles, resident Af) into cs double buffer.
#define PRODUCE(NT, bufv, chunkv)  do { \
  int posg_ = (chunkv)*16 + m; int swp_ = (posg_ & 7) << 4; \
  short8 Bfr[4]; \
  _Pragma("unroll") for (int kk = 0; kk < 4; ++kk) \
    Bfr[kk] = *(const short8*)((char*)xs + posg_*256 + (((kk<<6)+(kg<<4)) ^ swp_)); \
  _Pragma("unroll") for (int ti = 0; ti < NT; ++ti) { \
    f32x4 acc = (f32x4){0.f,0.f,0.f,0.f}; \
    _Pragma("unroll") for (int kk = 0; kk < 4; ++kk) \
      acc = __builtin_amdgcn_mfma_f32_16x16x32_bf16(Af[ti][kk], Bfr[kk], acc, 0, 0, 0); \
    int colL_ = (tbase + ti)*16 + (kg<<2); \
    unsigned lo_ = (unsigned)f2bf(acc[0]) | ((unsigned)f2bf(acc[1])<<16); \
    unsigned hi_ = (unsigned)f2bf(acc[2]) | ((unsigned)f2bf(acc[3])<<16); \
    int byte_ = (((bufv)*2 + dw)<<14) + (m<<10) + ((colL_<<1) ^ ((m&7)<<4)); \
    *(uint2*)((char*)cs + byte_) = make_uint2(lo_, hi_); \
  } } while(0)

// Heavy producer: 12 tiles in 3 batches of 4. Each batch: 16 W loads issued
// together (one L2-latency exposure), then 16 MFMAs — instead of 48 dependent
// load->MFMA pairs when Af[12][4] doesn't fit in registers.
#define PRODUCE_B12(bufv, chunkv)  do { \
  int posg_ = (chunkv)*16 + m; int swp_ = (posg_ & 7) << 4; \
  short8 Bfr[4]; \
  _Pragma("unroll") for (int kk = 0; kk < 4; ++kk) \
    Bfr[kk] = *(const short8*)((char*)xs + posg_*256 + (((kk<<6)+(kg<<4)) ^ swp_)); \
  _Pragma("unroll") for (int g = 0; g < 3; ++g) { \
    short8 Ag[4][4]; \
    _Pragma("unroll") for (int ti = 0; ti < 4; ++ti) \
      _Pragma("unroll") for (int kk = 0; kk < 4; ++kk) \
        Ag[ti][kk] = *(const short8*)(Wf + (size_t)(((dw*32 + tbase + g*4 + ti)*4 + kk)*64 + lane)*8); \
    _Pragma("unroll") for (int ti = 0; ti < 4; ++ti) { \
      f32x4 acc = (f32x4){0.f,0.f,0.f,0.f}; \
      _Pragma("unroll") for (int kk = 0; kk < 4; ++kk) \
        acc = __builtin_amdgcn_mfma_f32_16x16x32_bf16(Ag[ti][kk], Bfr[kk], acc, 0, 0, 0); \
      int colL_ = (tbase + g*4 + ti)*16 + (kg<<2); \
      unsigned lo_ = (unsigned)f2bf(acc[0]) | ((unsigned)f2bf(acc[1])<<16); \
      unsigned hi_ = (unsigned)f2bf(acc[2]) | ((unsigned)f2bf(acc[3])<<16); \
      int byte_ = (((bufv)*2 + dw)<<14) + (m<<10) + ((colL_<<1) ^ ((m&7)<<4)); \
      *(uint2*)((char*)cs + byte_) = make_uint2(lo_, hi_); \
    } \
  } } while(0)

#define SCAN_STEP(s) { \
  float ar = b2f((u16)(cw[s].x & 0xffffu)) + bv.x; \
  float br = b2f((u16)(cw[s].x >> 16)) + bv.y; \
  float cr = b2f((u16)(cw[s].y & 0xffffu)) + bv.z; \
  float dr = b2f((u16)(cw[s].y >> 16)) + bv.w; \
  float aa = sigmoidf_(ar); \
  h = aa*h + br*xf[s]; \
  yv[s] = cr*h + dr*xf[s]; }

// Fused coeff-GEMM + bidirectional scan (r9-proven structure, batched producer).
// Block = 512 thr (8 waves): waves 0-3 = scanners (+4 W-tiles, resident); waves
// 4-7 = producers (12 W-tiles in 3 register-batches). cs double-buffered,
// y accumulated in LDS (bf16).
template<int AXISW, int PART>
__global__ __launch_bounds__(512, 2) void scan_fused(const u16* __restrict__ Abf,
    const u16* __restrict__ Wf, const float* __restrict__ bias,
    u16* __restrict__ fusedP)
{
  __shared__ __align__(16) u16 xs[128*128];      // 32 KB, swizzled byte ^ ((pos&7)<<4)
  __shared__ __align__(16) u16 cs[2][2][16*512]; // 64 KB: [buf][dir][16 pos][512 cols]
  __shared__ __align__(16) u16 ysL[128*128];     // 32 KB bf16 partial y [pos][ch]
  int line = blockIdx.x;
  int b = line >> 7, l = line & 127;
  int t = threadIdx.x;
  int wv = t >> 6, lane = t & 63;
  int m = lane & 15, kg = lane >> 4;
  int dw = (wv >> 1) & 1;    // this wave's coeff direction

  // stage xp tile for the line (128 pos x 128 ch)
  #pragma unroll
  for (int i = 0; i < 4; ++i) {
    int idx = i*512 + t;
    int pos = idx >> 4, j = idx & 15;
    size_t row = AXISW ? ((size_t)(b<<14) + (l<<7) + pos)
                       : ((size_t)(b<<14) + (pos<<7) + l);
    short8 v = *(const short8*)(Abf + (row<<7) + (j<<3));
    int byte = pos*256 + ((j*16) ^ ((pos&7)<<4));
    *(short8*)((char*)xs + byte) = v;
  }

  if (wv < 4) {
    // ---------- scanner + light producer ----------
    int tbase = (wv & 1) * 4;
    short8 Af[4][4];
    #pragma unroll
    for (int ti = 0; ti < 4; ++ti)
      #pragma unroll
      for (int kk = 0; kk < 4; ++kk)
        Af[ti][kk] = *(const short8*)(Wf + (size_t)(((dw*32 + tbase + ti)*4 + kk)*64 + lane)*8);
    __syncthreads();                       // xs ready
    PRODUCE(4, 0, dw ? 7 : 0);
    __syncthreads();                       // cs[0] ready

    int sd = dw;
    int sc = ((wv & 1) << 6) + lane;       // scan channel 0..127
    float4 bv = *(const float4*)(bias + (sd << 9) + (sc << 2));
    float h = 0.f;

    #pragma unroll 1
    for (int k = 0; k < 8; ++k) {
      if (k < 7) PRODUCE(4, (k+1)&1, dw ? (6-k) : (k+1));
      int chunk = sd ? (7-k) : k;
      int csb = (((k&1)*2 + sd) << 14);
      uint2 cw[16];
      #pragma unroll
      for (int s = 0; s < 16; ++s)
        cw[s] = *(const uint2*)((char*)cs + csb + (s<<10) + ((sc<<3) ^ ((s&7)<<4)));
      float xf[16];
      #pragma unroll
      for (int s = 0; s < 16; ++s) {
        int pos = (chunk<<4) + s;
        xf[s] = b2f(*(const u16*)((char*)xs + pos*256 + ((sc<<1) ^ ((s&7)<<4))));
      }
      float yv[16];
      __builtin_amdgcn_s_setprio(1);
      if (sd == 0) {
        #pragma unroll
        for (int s = 0; s < 16; ++s) SCAN_STEP(s)
      } else {
        #pragma unroll
        for (int s = 15; s >= 0; --s) SCAN_STEP(s)
      }
      __builtin_amdgcn_s_setprio(0);
      u16* yrow = ysL + (chunk << 11) + sc;
      if (k <= 3) {
        #pragma unroll
        for (int s = 0; s < 16; ++s) yrow[s << 7] = f2bf(0.25f*yv[s]);
      } else {
        #pragma unroll
        for (int s = 0; s < 16; ++s) {
          float o = b2f(yrow[s << 7]);
          yrow[s << 7] = f2bf(o + 0.25f*yv[s]);
        }
      }
      __syncthreads();
    }
  } else {
    // ---------- heavy producer (batched) ----------
    int tbase = 8 + (wv & 1) * 12;
    __syncthreads();                       // xs ready
    PRODUCE_B12(0, dw ? 7 : 0);
    __syncthreads();                       // cs[0] ready
    #pragma unroll 1
    for (int k = 0; k < 8; ++k) {
      if (k < 7) PRODUCE_B12((k+1)&1, dw ? (6-k) : (k+1));
      __syncthreads();
    }
  }

  // cooperative coalesced writeout: 2048 short8 slots
  #pragma unroll
  for (int r = 0; r < 4; ++r) {
    int slot = r*512 + t;
    int pos = slot >> 4, j = slot & 15;
    short8 v = *(const short8*)(ysL + (pos << 7) + (j << 3));
    size_t rowg = AXISW ? ((size_t)(b<<14) + (l<<7) + pos)
                        : ((size_t)(b<<14) + (pos<<7) + l);
    u16* op = fusedP + (rowg << 7) + (j << 3);
    if (PART) {
      short8 o = *(const short8*)op;
      short8 rr;
      #pragma unroll
      for (int i = 0; i < 8; ++i) rr[i] = (short)f2bf(b2f((u16)v[i]) + b2f((u16)o[i]));
      *(short8*)op = rr;
    } else {
      *(short8*)op = v;
    }
  }
}

// GroupNorm stats over bf16 channels-last, coalesced short8 loads.
__global__ __launch_bounds__(256) void gn_stats_bf(const u16* __restrict__ X,
    float* __restrict__ stats)
{
  int b = blockIdx.x, chunk = blockIdx.y;
  const u16* base = X + ((size_t)b << 21) + ((size_t)chunk << 15);
  int t = threadIdx.x;
  float s = 0.f, q = 0.f;
  #pragma unroll 4
  for (int it = 0; it < 16; ++it) {
    short8 v = *(const short8*)(base + it*2048 + t*8);
    #pragma unroll
    for (int e = 0; e < 8; ++e) { float f = b2f((u16)v[e]); s += f; q += f*f; }
  }
  s += __shfl_xor(s, 16); q += __shfl_xor(q, 16);
  s += __shfl_xor(s, 32); q += __shfl_xor(q, 32);
  __shared__ float sg[32];
  if (t < 32) sg[t] = 0.f;
  __syncthreads();
  int lane = t & 63;
  if (lane < 16) { atomicAdd(&sg[lane], s); atomicAdd(&sg[16 + lane], q); }
  __syncthreads();
  if (t < 16) atomicAdd(&stats[b*16 + t], sg[t]);
  else if (t < 32) atomicAdd(&stats[64 + b*16 + (t - 16)], sg[t]);
}

// Apply GN1 + SiLU: read bf16, write bf16.
__global__ __launch_bounds__(256) void gn_apply(const u16* __restrict__ X,
    const float* __restrict__ stats, const float* __restrict__ gamma,
    const float* __restrict__ beta, u16* __restrict__ Xb)
{
  int i4 = blockIdx.x*256 + threadIdx.x;
  size_t base = (size_t)i4 << 2;
  int c4 = (int)(base & 127);
  size_t p = base >> 7;
  int b = (int)(p >> 14);
  int g = c4 >> 3;
  const float cnt = (float)(CPG*HW_);
  float mu = stats[b*16+g]/cnt;
  float var = stats[64+b*16+g]/cnt - mu*mu;
  float rs = rsqrtf(var + 1e-5f);
  ushort4 v = *(const ushort4*)(X + base);
  ushort4 o;
  o.x = f2bf(siluf_((b2f(v.x)-mu)*rs*gamma[c4+0]+beta[c4+0]));
  o.y = f2bf(siluf_((b2f(v.y)-mu)*rs*gamma[c4+1]+beta[c4+1]));
  o.z = f2bf(siluf_((b2f(v.z)-mu)*rs*gamma[c4+2]+beta[c4+2]));
  o.w = f2bf(siluf_((b2f(v.w)-mu)*rs*gamma[c4+3]+beta[c4+3]));
  *(ushort4*)(Xb + base) = o;
}

// Depthwise 3x3 with fused gate multiply: z = dw3x3(fused * gate), bf16 in/out.
__global__ __launch_bounds__(256) void dwconv(const u16* __restrict__ Z,
    const u16* __restrict__ G, const float* __restrict__ K9, u16* __restrict__ Outp)
{
  __shared__ float kk[1152];
  int t = threadIdx.x;
  for (int i = t; i < 1152; i += 256) kk[i] = K9[i];
  __syncthreads();
  int i4 = blockIdx.x*256 + t;
  size_t base = (size_t)i4 << 2;
  int c0 = (int)(base & 127);
  size_t p = base >> 7;
  int w = (int)(p & 127), h = (int)((p >> 7) & 127), b = (int)(p >> 14);
  float4 acc = make_float4(0.f,0.f,0.f,0.f);
  #pragma unroll
  for (int di = 0; di < 3; ++di) {
    int hy = h + di - 1;
    if ((unsigned)hy > 127u) continue;
    #pragma unroll
    for (int dj = 0; dj < 3; ++dj) {
      int wx = w + dj - 1;
      if ((unsigned)wx > 127u) continue;
      size_t p2 = ((size_t)b << 14) + (hy << 7) + wx;
      ushort4 zv = *(const ushort4*)(Z + (p2 << 7) + c0);
      ushort4 gv = *(const ushort4*)(G + (p2 << 7) + c0);
      int o = di*3 + dj;
      acc.x += b2f(zv.x) * b2f(gv.x) * kk[c0*9 + o];
      acc.y += b2f(zv.y) * b2f(gv.y) * kk[(c0+1)*9 + o];
      acc.z += b2f(zv.z) * b2f(gv.z) * kk[(c0+2)*9 + o];
      acc.w += b2f(zv.w) * b2f(gv.w) * kk[(c0+3)*9 + o];
    }
  }
  ushort4 ov;
  ov.x = f2bf(acc.x); ov.y = f2bf(acc.y); ov.z = f2bf(acc.z); ov.w = f2bf(acc.w);
  *(ushort4*)(Outp + base) = ov;
}

// GN2 apply + SiLU + transpose to channels-first fp32 output. Input bf16.
__global__ __launch_bounds__(256) void gn_final(const u16* __restrict__ Z,
    const float* __restrict__ stats, const float* __restrict__ gamma,
    const float* __restrict__ beta, float* __restrict__ out)
{
  __shared__ float ls[32][129];
  int w0 = blockIdx.x << 5, hh = blockIdx.y, b = blockIdx.z;
  size_t p0 = ((size_t)b << 14) + (hh << 7) + w0;
  int t = threadIdx.x;
  const float cnt = (float)(CPG*HW_);
  #pragma unroll
  for (int i = 0; i < 4; ++i) {
    int l = t + i*256;
    int row = l >> 5, c4 = (l & 31) << 2;
    ushort4 v = *(const ushort4*)(Z + ((p0 + row) << 7) + c4);
    int g = c4 >> 3;
    float mu = stats[b*16+g]/cnt;
    float var = stats[64+b*16+g]/cnt - mu*mu;
    float rs = rsqrtf(var + 1e-5f);
    float vals[4] = {b2f(v.x), b2f(v.y), b2f(v.z), b2f(v.w)};
    #pragma unroll
    for (int j = 0; j < 4; ++j) {
      float nv = (vals[j]-mu)*rs*gamma[c4+j] + beta[c4+j];
      ls[row][c4+j] = siluf_(nv);
    }
  }
  __syncthreads();
  int ww = t & 31, c0 = t >> 5;
  #pragma unroll
  for (int cc = c0; cc < 128; cc += 8) {
    out[(((size_t)(b*128 + cc)) << 14) + (hh << 7) + (w0 + ww)] = ls[ww][cc];
  }
}

extern "C" void kernel_launch(void* const* d_in, const int* in_sizes, int n_in,
                              void* d_out, int out_size, void* d_ws, size_t ws_size,
                              hipStream_t stream)
{
  (void)in_sizes; (void)n_in; (void)out_size; (void)ws_size;
  const float* x      = (const float*)d_in[0];
  const float* w_in   = (const float*)d_in[1];
  const float* g1g    = (const float*)d_in[2];
  const float* g1b    = (const float*)d_in[3];
  const float* w_gate = (const float*)d_in[4];
  const float* b_gate = (const float*)d_in[5];
  const float* dyn_w  = (const float*)d_in[6];
  const float* dyn_b  = (const float*)d_in[7];
  const float* dwk    = (const float*)d_in[8];
  const float* w_out  = (const float*)d_in[9];
  const float* g2g    = (const float*)d_in[10];
  const float* g2b    = (const float*)d_in[11];
  float* out = (float*)d_out;

  char* p = (char*)d_ws;
  u16*   Zbuf   = (u16*)p;              p += (size_t)S_*2;   // scratch for Zdw
  u16*   xpr    = (u16*)p;              p += (size_t)S_*2;   // xp_raw bf16; later Zout
  u16*   Abf    = (u16*)p;              p += (size_t)S_*2;   // xp (post GN1+SiLU) bf16
  u16*   fusedP = (u16*)p;              p += (size_t)S_*2;   // fused partial/final bf16
  u16*   Gbf    = (u16*)p;              p += (size_t)S_*2;   // gate bf16
  u16*   wfrag  = (u16*)p;              p += (size_t)262144*2;
  u16*   wgbf   = (u16*)p;              p += (size_t)16384*2;
  u16*   wobf   = (u16*)p;              p += (size_t)16384*2;
  u16*   wibf   = (u16*)p;              p += (size_t)16384*2;
  float* bperm  = (float*)p;            p += (size_t)2048*4;
  float* stats  = (float*)p;            p += (size_t)256*4;
  u16*   Zdw    = Zbuf;
  u16*   Zout   = xpr;                  // alias (xp_raw dead after gn_apply)

  prep_kernel<<<1225, 256, 0, stream>>>(dyn_w, dyn_b, w_gate, w_out, w_in,
                                        wfrag, bperm, wgbf, wobf, wibf, stats);
  mfma_inproj<<<1024, 256, 0, stream>>>(x, wibf, xpr);
  gn_stats_bf<<<dim3(4, 64), 256, 0, stream>>>(xpr, stats);
  gn_apply<<<8192, 256, 0, stream>>>(xpr, stats, g1g, g1b, Abf);

  scan_fused<1,0><<<512, 512, 0, stream>>>(Abf, wfrag, bperm, fusedP);
  scan_fused<0,1><<<512, 512, 0, stream>>>(Abf, wfrag + 2*65536, bperm + 1024, fusedP);

  mfma_nt128<1,1><<<1024, 256, 0, stream>>>(Abf, wgbf, b_gate, Gbf);
  dwconv<<<8192, 256, 0, stream>>>(fusedP, Gbf, dwk, Zdw);
  mfma_nt128<0,0><<<1024, 256, 0, stream>>>(Zdw, wobf, nullptr, Zout);
  gn_stats_bf<<<dim3(4, 64), 256, 0, stream>>>(Zout, stats + 128);
  gn_final<<<dim3(4, 128, 4), 256, 0, stream>>>(Zout, stats + 128, g2g, g2b, out);
}

// Round 16
// 199.335 us; speedup vs baseline: 1.5884x; 1.0567x over previous
//
#include <hip/hip_runtime.h>
#include <math.h>

#define B_ 4
#define C_ 128
#define HW_ 16384
#define P_ 65536
#define S_ 8388608   // B*C*H*W elements
#define CPG 8        // channels per group (128/16)

typedef unsigned short u16;
typedef __attribute__((ext_vector_type(8))) short short8;
typedef __attribute__((ext_vector_type(4))) float f32x4;

__device__ __forceinline__ float sigmoidf_(float x){ return 1.f/(1.f+__expf(-x)); }
__device__ __forceinline__ float siluf_(float x){ return x*sigmoidf_(x); }
__device__ __forceinline__ u16 f2bf(float f){
  unsigned x = __float_as_uint(f);
  return (u16)((x + 0x7fffu + ((x >> 16) & 1u)) >> 16);
}
__device__ __forceinline__ float b2f(u16 u){ return __uint_as_float(((unsigned)u) << 16); }

// Build wfrag (dyn_w in MFMA A-fragment order), bperm, wgbf, wobf, wibf, stats=0.
__global__ __launch_bounds__(256) void prep_kernel(const float* __restrict__ dyn_w,
    const float* __restrict__ dyn_b, const float* __restrict__ w_gate,
    const float* __restrict__ w_out, const float* __restrict__ w_in,
    u16* __restrict__ wfrag, float* __restrict__ bperm, u16* __restrict__ wgbf,
    u16* __restrict__ wobf, u16* __restrict__ wibf, float* __restrict__ stats)
{
  int idx = blockIdx.x*256 + threadIdx.x;
  if (idx < 262144) {
    int e = idx & 7, lane = (idx >> 3) & 63, kk = (idx >> 9) & 3;
    int ct = (idx >> 11) & 31, d = idx >> 16;
    int m = lane & 15, kg = lane >> 4;
    int col = ct*16 + m;
    int c = col >> 2, f = col & 3;
    int k = kk*32 + kg*8 + e;
    wfrag[idx] = f2bf(dyn_w[(size_t)((d*512) + f*128 + c)*128 + k]);
  } else if (idx < 264192) {
    int i2 = idx - 262144;
    int op = i2 & 511, d = i2 >> 9;
    bperm[i2] = dyn_b[d*512 + (op & 3)*128 + (op >> 2)];
  } else if (idx < 280576) {
    wgbf[idx - 264192] = f2bf(w_gate[idx - 264192]);
  } else if (idx < 296960) {
    wobf[idx - 280576] = f2bf(w_out[idx - 280576]);
  } else if (idx < 313344) {
    wibf[idx - 296960] = f2bf(w_in[idx - 296960]);
  } else if (idx < 313600) {
    stats[idx - 313344] = 0.f;
  }
}

// in_proj MFMA GEMM reading channels-first fp32 x directly.
__global__ __launch_bounds__(256) void mfma_inproj(const float* __restrict__ x,
    const u16* __restrict__ Wm, u16* __restrict__ Out)
{
  __shared__ __align__(16) u16 st[64*136];
  int t = threadIdx.x;
  int wv = t >> 6, lane = t & 63;
  int m = lane & 15, kg = lane >> 4;
  int pt = blockIdx.x << 6;
  int b = blockIdx.x >> 8;
  int hw0 = (blockIdx.x & 255) << 6;
  const float* xb = x + ((size_t)b << 21);

  short8 Af[4][4];
  #pragma unroll
  for (int rt = 0; rt < 4; ++rt) {
    int pos = hw0 + rt*16 + m;
    #pragma unroll
    for (int kk = 0; kk < 4; ++kk) {
      short8 f;
      #pragma unroll
      for (int e = 0; e < 8; ++e)
        f[e] = (short)f2bf(xb[(size_t)(kk*32 + kg*8 + e)*HW_ + pos]);
      Af[rt][kk] = f;
    }
  }
  #pragma unroll
  for (int ct2 = 0; ct2 < 2; ++ct2) {
    int ot = wv*32 + ct2*16;
    const u16* wr = Wm + ((size_t)(ot + m) << 7) + kg*8;
    short8 Bf[4];
    #pragma unroll
    for (int kk = 0; kk < 4; ++kk)
      Bf[kk] = *(const short8*)(wr + kk*32);
    f32x4 acc[4];
    #pragma unroll
    for (int rt = 0; rt < 4; ++rt) acc[rt] = (f32x4){0.f,0.f,0.f,0.f};
    #pragma unroll
    for (int rt = 0; rt < 4; ++rt)
      #pragma unroll
      for (int kk = 0; kk < 4; ++kk)
        acc[rt] = __builtin_amdgcn_mfma_f32_16x16x32_bf16(Af[rt][kk], Bf[kk], acc[rt], 0, 0, 0);
    #pragma unroll
    for (int rt = 0; rt < 4; ++rt) {
      #pragma unroll
      for (int r = 0; r < 4; ++r)
        st[(rt*16 + kg*4 + r)*136 + ot + m] = f2bf(acc[rt][r]);
    }
  }
  __syncthreads();
  #pragma unroll
  for (int i = 0; i < 4; ++i) {
    int slot = i*256 + t;
    int row = slot >> 4, j = slot & 15;
    short8 v = *(const short8*)(st + row*136 + (j << 3));
    *(short8*)(Out + ((size_t)(pt + row) << 7) + (j << 3)) = v;
  }
}

// MFMA NT GEMM, O=128, LDS-staged coalesced output.
template<int BIAS, int SIG>
__global__ __launch_bounds__(256) void mfma_nt128(const u16* __restrict__ X,
    const u16* __restrict__ Wm, const float* __restrict__ bias, u16* __restrict__ Out)
{
  __shared__ __align__(16) u16 st[64*136];
  int t = threadIdx.x;
  int wv = t >> 6, lane = t & 63;
  int m = lane & 15, kg = lane >> 4;
  int pt = blockIdx.x << 6;

  short8 Af[4][4];
  #pragma unroll
  for (int rt = 0; rt < 4; ++rt) {
    const u16* ar = X + ((size_t)(pt + rt*16 + m) << 7) + kg*8;
    #pragma unroll
    for (int kk = 0; kk < 4; ++kk)
      Af[rt][kk] = *(const short8*)(ar + kk*32);
  }
  #pragma unroll
  for (int ct2 = 0; ct2 < 2; ++ct2) {
    int ot = wv*32 + ct2*16;
    const u16* wr = Wm + ((size_t)(ot + m) << 7) + kg*8;
    short8 Bf[4];
    #pragma unroll
    for (int kk = 0; kk < 4; ++kk)
      Bf[kk] = *(const short8*)(wr + kk*32);
    f32x4 acc[4];
    #pragma unroll
    for (int rt = 0; rt < 4; ++rt) acc[rt] = (f32x4){0.f,0.f,0.f,0.f};
    #pragma unroll
    for (int rt = 0; rt < 4; ++rt)
      #pragma unroll
      for (int kk = 0; kk < 4; ++kk)
        acc[rt] = __builtin_amdgcn_mfma_f32_16x16x32_bf16(Af[rt][kk], Bf[kk], acc[rt], 0, 0, 0);
    float bv = BIAS ? bias[ot + m] : 0.f;
    #pragma unroll
    for (int rt = 0; rt < 4; ++rt) {
      #pragma unroll
      for (int r = 0; r < 4; ++r) {
        float v = acc[rt][r] + bv;
        if (SIG) v = sigmoidf_(v);
        st[(rt*16 + kg*4 + r)*136 + ot + m] = f2bf(v);
      }
    }
  }
  __syncthreads();
  #pragma unroll
  for (int i = 0; i < 4; ++i) {
    int slot = i*256 + t;
    int row = slot >> 4, j = slot & 15;
    short8 v = *(const short8*)(st + row*136 + (j << 3));
    *(short8*)(Out + ((size_t)(pt + row) << 7) + (j << 3)) = v;
  }
}

// Produce 16-pos coeff chunk into cs double buffer (bank-swizzled).
#define PRODUCE(NT, bufv, chunkv)  do { \
  int posg_ = (chunkv)*16 + m; int swp_ = (posg_ & 7) << 4; \
  short8 Bfr[4]; \
  _Pragma("unroll") for (int kk = 0; kk < 4; ++kk) \
    Bfr[kk] = *(const short8*)((char*)xs + posg_*256 + (((kk<<6)+(kg<<4)) ^ swp_)); \
  _Pragma("unroll") for (int ti = 0; ti < NT; ++ti) { \
    f32x4 acc = (f32x4){0.f,0.f,0.f,0.f}; \
    _Pragma("unroll") for (int kk = 0; kk < 4; ++kk) \
      acc = __builtin_amdgcn_mfma_f32_16x16x32_bf16(Af[ti][kk], Bfr[kk], acc, 0, 0, 0); \
    int colL_ = (tbase + ti)*16 + (kg<<2); \
    unsigned lo_ = (unsigned)f2bf(acc[0]) | (((unsigned)f2bf(acc[1]))<<16); \
    unsigned hi_ = (unsigned)f2bf(acc[2]) | (((unsigned)f2bf(acc[3]))<<16); \
    int byte_ = (((bufv)*2 + dw)<<14) + (m<<10) + ((colL_<<1) ^ ((m&7)<<4)); \
    *(uint2*)((char*)cs + byte_) = make_uint2(lo_, hi_); \
  } } while(0)

#define SCAN_STEP(s) { \
  float ar = b2f((u16)(cw[s].x & 0xffffu)) + bv.x; \
  float br = b2f((u16)(cw[s].x >> 16)) + bv.y; \
  float cr = b2f((u16)(cw[s].y & 0xffffu)) + bv.z; \
  float dr = b2f((u16)(cw[s].y >> 16)) + bv.w; \
  float aa = sigmoidf_(ar); \
  h = aa*h + br*xf[s]; \
  yv[s] = cr*h + dr*xf[s]; }

// Fused coeff-GEMM + bidirectional scan (r9-proven structure).
// Block = 512 thr (8 waves): waves 0-3 = scanners (+4 W-tiles, resident); waves
// 4-7 = producers (12 W-tiles). cs double-buffered, y accumulated in LDS (bf16).
template<int AXISW, int PART>
__global__ __launch_bounds__(512, 2) void scan_fused(const u16* __restrict__ Abf,
    const u16* __restrict__ Wf, const float* __restrict__ bias,
    u16* __restrict__ fusedP)
{
  __shared__ __align__(16) u16 xs[128*128];      // 32 KB, swizzled byte ^ ((pos&7)<<4)
  __shared__ __align__(16) u16 cs[2][2][16*512]; // 64 KB: [buf][dir][16 pos][512 cols]
  __shared__ __align__(16) u16 ysL[128*128];     // 32 KB bf16 partial y [pos][ch]
  int line = blockIdx.x;
  int b = line >> 7, l = line & 127;
  int t = threadIdx.x;
  int wv = t >> 6, lane = t & 63;
  int m = lane & 15, kg = lane >> 4;
  int dw = (wv >> 1) & 1;    // this wave's coeff direction

  // stage xp tile for the line (128 pos x 128 ch)
  #pragma unroll
  for (int i = 0; i < 4; ++i) {
    int idx = i*512 + t;
    int pos = idx >> 4, j = idx & 15;
    size_t row = AXISW ? ((size_t)(b<<14) + (l<<7) + pos)
                       : ((size_t)(b<<14) + (pos<<7) + l);
    short8 v = *(const short8*)(Abf + (row<<7) + (j<<3));
    int byte = pos*256 + ((j*16) ^ ((pos&7)<<4));
    *(short8*)((char*)xs + byte) = v;
  }

  if (wv < 4) {
    // ---------- scanner + light producer ----------
    int tbase = (wv & 1) * 4;
    short8 Af[4][4];
    #pragma unroll
    for (int ti = 0; ti < 4; ++ti)
      #pragma unroll
      for (int kk = 0; kk < 4; ++kk)
        Af[ti][kk] = *(const short8*)(Wf + (size_t)(((dw*32 + tbase + ti)*4 + kk)*64 + lane)*8);
    __syncthreads();                       // xs ready
    PRODUCE(4, 0, dw ? 7 : 0);
    __syncthreads();                       // cs[0] ready

    int sd = dw;
    int sc = ((wv & 1) << 6) + lane;       // scan channel 0..127
    float4 bv = *(const float4*)(bias + (sd << 9) + (sc << 2));
    float h = 0.f;

    #pragma unroll 1
    for (int k = 0; k < 8; ++k) {
      if (k < 7) PRODUCE(4, (k+1)&1, dw ? (6-k) : (k+1));
      int chunk = sd ? (7-k) : k;
      int csb = (((k&1)*2 + sd) << 14);
      uint2 cw[16];
      #pragma unroll
      for (int s = 0; s < 16; ++s)
        cw[s] = *(const uint2*)((char*)cs + csb + (s<<10) + ((sc<<3) ^ ((s&7)<<4)));
      float xf[16];
      #pragma unroll
      for (int s = 0; s < 16; ++s) {
        int pos = (chunk<<4) + s;
        xf[s] = b2f(*(const u16*)((char*)xs + pos*256 + ((sc<<1) ^ ((s&7)<<4))));
      }
      float yv[16];
      __builtin_amdgcn_s_setprio(1);
      if (sd == 0) {
        #pragma unroll
        for (int s = 0; s < 16; ++s) SCAN_STEP(s)
      } else {
        #pragma unroll
        for (int s = 15; s >= 0; --s) SCAN_STEP(s)
      }
      __builtin_amdgcn_s_setprio(0);
      u16* yrow = ysL + (chunk << 11) + sc;
      if (k <= 3) {
        #pragma unroll
        for (int s = 0; s < 16; ++s) yrow[s << 7] = f2bf(0.25f*yv[s]);
      } else {
        #pragma unroll
        for (int s = 0; s < 16; ++s) {
          float o = b2f(yrow[s << 7]);
          yrow[s << 7] = f2bf(o + 0.25f*yv[s]);
        }
      }
      __syncthreads();
    }
  } else {
    // ---------- heavy producer ----------
    int tbase = 8 + (wv & 1) * 12;
    short8 Af[12][4];
    #pragma unroll
    for (int ti = 0; ti < 12; ++ti)
      #pragma unroll
      for (int kk = 0; kk < 4; ++kk)
        Af[ti][kk] = *(const short8*)(Wf + (size_t)(((dw*32 + tbase + ti)*4 + kk)*64 + lane)*8);
    __syncthreads();                       // xs ready
    PRODUCE(12, 0, dw ? 7 : 0);
    __syncthreads();                       // cs[0] ready
    #pragma unroll 1
    for (int k = 0; k < 8; ++k) {
      if (k < 7) PRODUCE(12, (k+1)&1, dw ? (6-k) : (k+1));
      __syncthreads();
    }
  }

  // cooperative coalesced writeout: 2048 short8 slots
  #pragma unroll
  for (int r = 0; r < 4; ++r) {
    int slot = r*512 + t;
    int pos = slot >> 4, j = slot & 15;
    short8 v = *(const short8*)(ysL + (pos << 7) + (j << 3));
    size_t rowg = AXISW ? ((size_t)(b<<14) + (l<<7) + pos)
                        : ((size_t)(b<<14) + (pos<<7) + l);
    u16* op = fusedP + (rowg << 7) + (j << 3);
    if (PART) {
      short8 o = *(const short8*)op;
      short8 rr;
      #pragma unroll
      for (int i = 0; i < 8; ++i) rr[i] = (short)f2bf(b2f((u16)v[i]) + b2f((u16)o[i]));
      *(short8*)op = rr;
    } else {
      *(short8*)op = v;
    }
  }
}

// GroupNorm stats over bf16 channels-last, coalesced short8 loads.
__global__ __launch_bounds__(256) void gn_stats_bf(const u16* __restrict__ X,
    float* __restrict__ stats)
{
  int b = blockIdx.x, chunk = blockIdx.y;
  const u16* base = X + ((size_t)b << 21) + ((size_t)chunk << 15);
  int t = threadIdx.x;
  float s = 0.f, q = 0.f;
  #pragma unroll 4
  for (int it = 0; it < 16; ++it) {
    short8 v = *(const short8*)(base + it*2048 + t*8);
    #pragma unroll
    for (int e = 0; e < 8; ++e) { float f = b2f((u16)v[e]); s += f; q += f*f; }
  }
  s += __shfl_xor(s, 16); q += __shfl_xor(q, 16);
  s += __shfl_xor(s, 32); q += __shfl_xor(q, 32);
  __shared__ float sg[32];
  if (t < 32) sg[t] = 0.f;
  __syncthreads();
  int lane = t & 63;
  if (lane < 16) { atomicAdd(&sg[lane], s); atomicAdd(&sg[16 + lane], q); }
  __syncthreads();
  if (t < 16) atomicAdd(&stats[b*16 + t], sg[t]);
  else if (t < 32) atomicAdd(&stats[64 + b*16 + (t - 16)], sg[t]);
}

// Apply GN1 + SiLU: read bf16, write bf16.
__global__ __launch_bounds__(256) void gn_apply(const u16* __restrict__ X,
    const float* __restrict__ stats, const float* __restrict__ gamma,
    const float* __restrict__ beta, u16* __restrict__ Xb)
{
  int i4 = blockIdx.x*256 + threadIdx.x;
  size_t base = (size_t)i4 << 2;
  int c4 = (int)(base & 127);
  size_t p = base >> 7;
  int b = (int)(p >> 14);
  int g = c4 >> 3;
  const float cnt = (float)(CPG*HW_);
  float mu = stats[b*16+g]/cnt;
  float var = stats[64+b*16+g]/cnt - mu*mu;
  float rs = rsqrtf(var + 1e-5f);
  ushort4 v = *(const ushort4*)(X + base);
  ushort4 o;
  o.x = f2bf(siluf_((b2f(v.x)-mu)*rs*gamma[c4+0]+beta[c4+0]));
  o.y = f2bf(siluf_((b2f(v.y)-mu)*rs*gamma[c4+1]+beta[c4+1]));
  o.z = f2bf(siluf_((b2f(v.z)-mu)*rs*gamma[c4+2]+beta[c4+2]));
  o.w = f2bf(siluf_((b2f(v.w)-mu)*rs*gamma[c4+3]+beta[c4+3]));
  *(ushort4*)(Xb + base) = o;
}

// Depthwise 3x3 with fused gate multiply: z = dw3x3(fused * gate), bf16 in/out.
__global__ __launch_bounds__(256) void dwconv(const u16* __restrict__ Z,
    const u16* __restrict__ G, const float* __restrict__ K9, u16* __restrict__ Outp)
{
  __shared__ float kk[1152];
  int t = threadIdx.x;
  for (int i = t; i < 1152; i += 256) kk[i] = K9[i];
  __syncthreads();
  int i4 = blockIdx.x*256 + t;
  size_t base = (size_t)i4 << 2;
  int c0 = (int)(base & 127);
  size_t p = base >> 7;
  int w = (int)(p & 127), h = (int)((p >> 7) & 127), b = (int)(p >> 14);
  float4 acc = make_float4(0.f,0.f,0.f,0.f);
  #pragma unroll
  for (int di = 0; di < 3; ++di) {
    int hy = h + di - 1;
    if ((unsigned)hy > 127u) continue;
    #pragma unroll
    for (int dj = 0; dj < 3; ++dj) {
      int wx = w + dj - 1;
      if ((unsigned)wx > 127u) continue;
      size_t p2 = ((size_t)b << 14) + (hy << 7) + wx;
      ushort4 zv = *(const ushort4*)(Z + (p2 << 7) + c0);
      ushort4 gv = *(const ushort4*)(G + (p2 << 7) + c0);
      int o = di*3 + dj;
      acc.x += b2f(zv.x) * b2f(gv.x) * kk[c0*9 + o];
      acc.y += b2f(zv.y) * b2f(gv.y) * kk[(c0+1)*9 + o];
      acc.z += b2f(zv.z) * b2f(gv.z) * kk[(c0+2)*9 + o];
      acc.w += b2f(zv.w) * b2f(gv.w) * kk[(c0+3)*9 + o];
    }
  }
  ushort4 ov;
  ov.x = f2bf(acc.x); ov.y = f2bf(acc.y); ov.z = f2bf(acc.z); ov.w = f2bf(acc.w);
  *(ushort4*)(Outp + base) = ov;
}

// GN2 apply + SiLU + transpose to channels-first fp32 output. Input bf16.
__global__ __launch_bounds__(256) void gn_final(const u16* __restrict__ Z,
    const float* __restrict__ stats, const float* __restrict__ gamma,
    const float* __restrict__ beta, float* __restrict__ out)
{
  __shared__ float ls[32][129];
  int w0 = blockIdx.x << 5, hh = blockIdx.y, b = blockIdx.z;
  size_t p0 = ((size_t)b << 14) + (hh << 7) + w0;
  int t = threadIdx.x;
  const float cnt = (float)(CPG*HW_);
  #pragma unroll
  for (int i = 0; i < 4; ++i) {
    int l = t + i*256;
    int row = l >> 5, c4 = (l & 31) << 2;
    ushort4 v = *(const ushort4*)(Z + ((p0 + row) << 7) + c4);
    int g = c4 >> 3;
    float mu = stats[b*16+g]/cnt;
    float var = stats[64+b*16+g]/cnt - mu*mu;
    float rs = rsqrtf(var + 1e-5f);
    float vals[4] = {b2f(v.x), b2f(v.y), b2f(v.z), b2f(v.w)};
    #pragma unroll
    for (int j = 0; j < 4; ++j) {
      float nv = (vals[j]-mu)*rs*gamma[c4+j] + beta[c4+j];
      ls[row][c4+j] = siluf_(nv);
    }
  }
  __syncthreads();
  int ww = t & 31, c0 = t >> 5;
  #pragma unroll
  for (int cc = c0; cc < 128; cc += 8) {
    out[(((size_t)(b*128 + cc)) << 14) + (hh << 7) + (w0 + ww)] = ls[ww][cc];
  }
}

extern "C" void kernel_launch(void* const* d_in, const int* in_sizes, int n_in,
                              void* d_out, int out_size, void* d_ws, size_t ws_size,
                              hipStream_t stream)
{
  (void)in_sizes; (void)n_in; (void)out_size; (void)ws_size;
  const float* x      = (const float*)d_in[0];
  const float* w_in   = (const float*)d_in[1];
  const float* g1g    = (const float*)d_in[2];
  const float* g1b    = (const float*)d_in[3];
  const float* w_gate = (const float*)d_in[4];
  const float* b_gate = (const float*)d_in[5];
  const float* dyn_w  = (const float*)d_in[6];
  const float* dyn_b  = (const float*)d_in[7];
  const float* dwk    = (const float*)d_in[8];
  const float* w_out  = (const float*)d_in[9];
  const float* g2g    = (const float*)d_in[10];
  const float* g2b    = (const float*)d_in[11];
  float* out = (float*)d_out;

  char* p = (char*)d_ws;
  u16*   Zbuf   = (u16*)p;              p += (size_t)S_*2;   // scratch for Zdw
  u16*   xpr    = (u16*)p;              p += (size_t)S_*2;   // xp_raw bf16; later Zout
  u16*   Abf    = (u16*)p;              p += (size_t)S_*2;   // xp (post GN1+SiLU) bf16
  u16*   fusedP = (u16*)p;              p += (size_t)S_*2;   // fused partial/final bf16
  u16*   Gbf    = (u16*)p;              p += (size_t)S_*2;   // gate bf16
  u16*   wfrag  = (u16*)p;              p += (size_t)262144*2;
  u16*   wgbf   = (u16*)p;              p += (size_t)16384*2;
  u16*   wobf   = (u16*)p;              p += (size_t)16384*2;
  u16*   wibf   = (u16*)p;              p += (size_t)16384*2;
  float* bperm  = (float*)p;            p += (size_t)2048*4;
  float* stats  = (float*)p;            p += (size_t)256*4;
  u16*   Zdw    = Zbuf;
  u16*   Zout   = xpr;                  // alias (xp_raw dead after gn_apply)

  prep_kernel<<<1225, 256, 0, stream>>>(dyn_w, dyn_b, w_gate, w_out, w_in,
                                        wfrag, bperm, wgbf, wobf, wibf, stats);
  mfma_inproj<<<1024, 256, 0, stream>>>(x, wibf, xpr);
  gn_stats_bf<<<dim3(4, 64), 256, 0, stream>>>(xpr, stats);
  gn_apply<<<8192, 256, 0, stream>>>(xpr, stats, g1g, g1b, Abf);

  scan_fused<1,0><<<512, 512, 0, stream>>>(Abf, wfrag, bperm, fusedP);
  scan_fused<0,1><<<512, 512, 0, stream>>>(Abf, wfrag + 2*65536, bperm + 1024, fusedP);

  mfma_nt128<1,1><<<1024, 256, 0, stream>>>(Abf, wgbf, b_gate, Gbf);
  dwconv<<<8192, 256, 0, stream>>>(fusedP, Gbf, dwk, Zdw);
  mfma_nt128<0,0><<<1024, 256, 0, stream>>>(Zdw, wobf, nullptr, Zout);
  gn_stats_bf<<<dim3(4, 64), 256, 0, stream>>>(Zout, stats + 128);
  gn_final<<<dim3(4, 128, 4), 256, 0, stream>>>(Zout, stats + 128, g2g, g2b, out);
}